// Round 1
// 380.889 us; speedup vs baseline: 1.0808x; 1.0808x over previous
//
#include <hip/hip_runtime.h>
#include <stdint.h>

// ---------------------------------------------------------------------------
// Sparse attention, MI355X. f32 I/O, bf16 MFMA internals.
//   0) xb = bf16(x); Wcat = bf16([Wv; Wq[512:]; Wk[512:]]); Wob = bf16(Wo)
//   1) fused proj GEMM: [qkv[:,:512] | vg | qg | kg] = xb @ Wcat^T + bcat
//   2) qkv[:, 512:] = sparse_attention(qg, kg, vg, mask)
//   3) out(f32) = qkv @ Wob^T + bo
// GEMMs this round: 256x256 tile, BK=32, 512 threads (8 waves 2x4),
// 3-buffer depth-2 pipeline with counted s_waitcnt vmcnt(8) + raw s_barrier
// (never drains vmcnt to 0 in the main loop -> global-load latency hidden
// under 2 compute phases instead of exposed at every __syncthreads drain).
// Chunked LDS frag layout (conflict-free, measured 0 conflicts) + linear
// global_load_lds dest with pre-swizzled per-lane global source.
// XCD swizzle: each XCD owns an 8-row-tile band x all col tiles.
// ---------------------------------------------------------------------------

typedef __bf16 bf16_t;
typedef __bf16 bf16x4 __attribute__((ext_vector_type(4)));
typedef __bf16 bf16x8 __attribute__((ext_vector_type(8)));
typedef float floatx4 __attribute__((ext_vector_type(4)));

#define MFMA16(a, b, c) __builtin_amdgcn_mfma_f32_16x16x32_bf16((a), (b), (c), 0, 0, 0)

// async global->LDS, 16B per lane; LDS dest = wave-uniform base + lane*16
__device__ __forceinline__ void glds16(const bf16_t* g, const bf16_t* lds_base) {
  __builtin_amdgcn_global_load_lds(
      (const __attribute__((address_space(1))) uint32_t*)(uintptr_t)g,
      (__attribute__((address_space(3))) uint32_t*)(uintptr_t)lds_base, 16, 0, 0);
}

#define VMCNT(n)  asm volatile("s_waitcnt vmcnt(" #n ")" ::: "memory")
#define LGKMCNT0  asm volatile("s_waitcnt lgkmcnt(0)" ::: "memory")
#define SBAR      __builtin_amdgcn_s_barrier()
#define SCHED0    __builtin_amdgcn_sched_barrier(0)

// ---------------------------------------------------------------------------
__global__ void cvt_f32_bf16(const float* __restrict__ src, bf16_t* __restrict__ dst, int n) {
  const int i = (blockIdx.x * 256 + threadIdx.x) * 4;
  if (i < n) {
    float4 v = *(const float4*)(src + i);
    bf16x4 d = {(bf16_t)v.x, (bf16_t)v.y, (bf16_t)v.z, (bf16_t)v.w};
    *(bf16x4*)(dst + i) = d;
  }
}

// bcat = [bv(1024); bq[512:](512); bk[512:](512)]  (f32, 2048)
__global__ void pack_bias(const float* __restrict__ bv, const float* __restrict__ bq,
                          const float* __restrict__ bk, float* __restrict__ bcat) {
  const int i = blockIdx.x * 256 + threadIdx.x;  // 2048 threads
  float v;
  if (i < 1024) v = bv[i];
  else if (i < 1536) v = bq[i - 512];
  else v = bk[i - 1024];
  bcat[i] = v;
}

// ---------------------------------------------------------------------------
// 256x256 GEMM core. A: (M x 1024) bf16, W: (N x 1024) bf16, K-contiguous.
// 512 threads = 8 waves in 2x4; wave output 128x64 -> acc[8][4] floatx4.
// LDS chunk layout per buffer: chunk c (0..1023) of 8 bf16 holds
//   Mat[base + (c&255)][kt*32 + (c>>8)*8 .. +8]   (conflict-free reads).
// Stage: thread tid loads chunks {tid, tid+512} of A and of B (4x glds16).
// Pipeline: 3 buffers; at tile t stage tile t+2 into buf[(t+2)%3] (freed at
// t-1), wait vmcnt(8) (stages t+1,t+2 stay in flight), barrier, compute
// buf[t%3], lgkmcnt(0)+barrier.
// ---------------------------------------------------------------------------
#define G256_SETUP(A_, W_, ROW0_, COL0_)                                        \
  __shared__ bf16_t As[3][8192];                                                \
  __shared__ bf16_t Bs[3][8192];                                                \
  const int tid = threadIdx.x;                                                  \
  const int w = tid >> 6, l = tid & 63;                                         \
  const int lq = l >> 4, lm = l & 15;                                           \
  const int wr = (w >> 2) << 7;   /* wave row offset 0/128 */                   \
  const int wc = (w & 3) << 6;    /* wave col offset 0/64/128/192 */            \
  const long row0 = (ROW0_);                                                    \
  const long col0 = (COL0_);                                                    \
  floatx4 acc[8][4];                                                            \
  { floatx4 z = {0.f, 0.f, 0.f, 0.f};                                           \
    _Pragma("unroll") for (int i = 0; i < 8; ++i)                               \
    _Pragma("unroll") for (int j = 0; j < 4; ++j) acc[i][j] = z; }              \
  const int c1i = tid + 512;                                                    \
  const bf16_t* gA0 = (A_) + (row0 + (tid & 255)) * 1024 + ((tid >> 8) << 3);   \
  const bf16_t* gA1 = (A_) + (row0 + (c1i & 255)) * 1024 + ((c1i >> 8) << 3);   \
  const bf16_t* gB0 = (W_) + (col0 + (tid & 255)) * 1024 + ((tid >> 8) << 3);   \
  const bf16_t* gB1 = (W_) + (col0 + (c1i & 255)) * 1024 + ((c1i >> 8) << 3);   \
  const int lo0 = (w << 6) << 3;          /* wave-uniform LDS elem offset */    \
  const int lo1 = ((w << 6) + 512) << 3;

#define G256_STAGE(s)                                                           \
  glds16(gA0, &As[s][0] + lo0);                                                 \
  glds16(gA1, &As[s][0] + lo1);                                                 \
  glds16(gB0, &Bs[s][0] + lo0);                                                 \
  glds16(gB1, &Bs[s][0] + lo1);                                                 \
  gA0 += 32; gA1 += 32; gB0 += 32; gB1 += 32;

#define G256_COMPUTE(s)                                                         \
  { bf16x8 af[8], bfr[4];                                                       \
    _Pragma("unroll") for (int mt = 0; mt < 8; ++mt)                            \
      af[mt] = *(const bf16x8*)(&As[s][0] + ((lq << 8) + wr + mt * 16 + lm) * 8); \
    _Pragma("unroll") for (int nt = 0; nt < 4; ++nt)                            \
      bfr[nt] = *(const bf16x8*)(&Bs[s][0] + ((lq << 8) + wc + nt * 16 + lm) * 8); \
    __builtin_amdgcn_s_setprio(1);                                              \
    _Pragma("unroll") for (int mt = 0; mt < 8; ++mt)                            \
      _Pragma("unroll") for (int nt = 0; nt < 4; ++nt)                          \
        acc[mt][nt] = MFMA16(af[mt], bfr[nt], acc[mt][nt]);                     \
    __builtin_amdgcn_s_setprio(0); }

#define G256_ITER(cs, ss)                                                       \
  G256_STAGE(ss)                                                                \
  VMCNT(8); SBAR; SCHED0;                                                       \
  G256_COMPUTE(cs)                                                              \
  LGKMCNT0; SBAR; SCHED0;

// K = 1024 -> 32 K-tiles. Main loop covers t = 0..29; tail t = 30, 31.
#define G256_MAIN                                                               \
  G256_STAGE(0)                                                                 \
  G256_STAGE(1)                                                                 \
  for (int t3 = 0; t3 < 10; ++t3) {                                             \
    G256_ITER(0, 2)                                                             \
    G256_ITER(1, 0)                                                             \
    G256_ITER(2, 1)                                                             \
  }                                                                             \
  VMCNT(4); SBAR; SCHED0;                                                       \
  G256_COMPUTE(0)                                                               \
  VMCNT(0); SBAR; SCHED0;                                                       \
  G256_COMPUTE(1)

// out-projection GEMM: M=16384, N=1024 -> 64 x 4 tiles = 256 blocks.
// XCD swizzle: xcd = n&7 owns row band [xcd*8, xcd*8+8) x all 4 col tiles.
__global__ __launch_bounds__(512, 2)
void gemm_bt(const bf16_t* __restrict__ A, const bf16_t* __restrict__ W,
             const float* __restrict__ bias, float* __restrict__ C, int ldc) {
  const int n = blockIdx.x, xcd = n & 7, j = n >> 3;  // j in [0,32)
  G256_SETUP(A, W, (long)(xcd * 8 + (j & 7)) * 256, (long)(j >> 3) * 256)
  G256_MAIN
#pragma unroll
  for (int nt = 0; nt < 4; ++nt) {
    const long col = col0 + wc + nt * 16 + lm;
    const float bc = bias[col];
#pragma unroll
    for (int mt = 0; mt < 8; ++mt) {
#pragma unroll
      for (int r = 0; r < 4; ++r) {
        const long row = row0 + wr + mt * 16 + lq * 4 + r;
        C[row * (long)ldc + col] = acc[mt][nt][r] + bc;
      }
    }
  }
}

// fused projection GEMM: M=16384, N=2048 -> 64 x 8 tiles = 512 blocks.
// cols [0,512)->qkv, [512,1024)->vg, [1024,1536)->qg, [1536,2048)->kg
__global__ __launch_bounds__(512, 2)
void gemm_proj(const bf16_t* __restrict__ A, const bf16_t* __restrict__ Wcat,
               const float* __restrict__ bcat, bf16_t* __restrict__ qkv,
               bf16_t* __restrict__ vg, bf16_t* __restrict__ qg,
               bf16_t* __restrict__ kg) {
  const int n = blockIdx.x, xcd = n & 7, j = n >> 3;  // j in [0,64)
  G256_SETUP(A, Wcat, (long)(xcd * 8 + (j & 7)) * 256, (long)(j >> 3) * 256)
  G256_MAIN
  bf16_t* dst; long ld, cofs;
  if (col0 < 512)       { dst = qkv; ld = 1024; cofs = 0; }
  else if (col0 < 1024) { dst = vg;  ld = 512;  cofs = 512; }
  else if (col0 < 1536) { dst = qg;  ld = 512;  cofs = 1024; }
  else                  { dst = kg;  ld = 512;  cofs = 1536; }
#pragma unroll
  for (int nt = 0; nt < 4; ++nt) {
    const long col = col0 + wc + nt * 16 + lm;
    const float bc = bcat[col];
    const long cl = col - cofs;
#pragma unroll
    for (int mt = 0; mt < 8; ++mt) {
#pragma unroll
      for (int r = 0; r < 4; ++r) {
        const long row = row0 + wr + mt * 16 + lq * 4 + r;
        dst[row * ld + cl] = (bf16_t)(acc[mt][nt][r] + bc);
      }
    }
  }
}

// ---------------------------------------------------------------------------
// Sparse attention for global heads. Block = (qt, h, b): 64 query rows,
// 256 selected keys: token(l) = 64*(l>>2) + 32 + 4*h + (l&3).
// ---------------------------------------------------------------------------
__global__ __launch_bounds__(256, 1)
void attn_sparse(const bf16_t* __restrict__ qg, const bf16_t* __restrict__ kg,
                 const bf16_t* __restrict__ vg, const int* __restrict__ mask,
                 bf16_t* __restrict__ qkv) {
  __shared__ bf16_t Ks[16384];        // frag-order: chunk = kq*256 + lkey
  __shared__ bf16_t Vt[64 * 264];     // Vt[d][lkey], row stride 264 (+8 pad)
  __shared__ bf16_t Ps[4 * 16 * 136]; // per-wave P half-tile, stride 136 (+8 pad)
  __shared__ int smask[256];

  const int tid = threadIdx.x;
  const int b = blockIdx.z, h = blockIdx.y, qt = blockIdx.x;

  {
    const int lk = tid;
    const int token = ((lk >> 2) << 6) + 32 + (h << 2) + (lk & 3);
    const size_t rowi = (size_t)(b * 4096 + token);
    const uint4* ksrc = (const uint4*)(kg + rowi * 512 + h * 64);
#pragma unroll
    for (int kq = 0; kq < 8; ++kq)
      *(uint4*)(Ks + (kq * 256 + lk) * 8) = ksrc[kq];
    const bf16_t* vsrc = vg + rowi * 512 + h * 64;
#pragma unroll
    for (int i = 0; i < 8; ++i) {
      bf16x8 vv = *(const bf16x8*)(vsrc + i * 8);
#pragma unroll
      for (int j = 0; j < 8; ++j) Vt[(i * 8 + j) * 264 + lk] = vv[j];
    }
    smask[lk] = mask[b * 4096 + token];
  }
  __syncthreads();

  const int w = tid >> 6, l = tid & 63, lq = l >> 4, lm = l & 15;
  const int mrow = (qt << 6) + (w << 4);

  const bf16_t* qrow = qg + (size_t)(b * 4096 + mrow + lm) * 512 + h * 64 + lq * 8;
  bf16x8 aq0 = *(const bf16x8*)qrow;
  bf16x8 aq1 = *(const bf16x8*)(qrow + 32);

  floatx4 zero4 = {0.f, 0.f, 0.f, 0.f};
  floatx4 s[16];
#pragma unroll
  for (int t = 0; t < 16; ++t) {
    bf16x8 kb0 = *(const bf16x8*)(Ks + (lq * 256 + t * 16 + lm) * 8);
    bf16x8 kb1 = *(const bf16x8*)(Ks + ((4 + lq) * 256 + t * 16 + lm) * 8);
    floatx4 z = zero4;
    z = MFMA16(aq0, kb0, z);
    z = MFMA16(aq1, kb1, z);
    s[t] = z;
  }

  float rmax[4] = {-1e30f, -1e30f, -1e30f, -1e30f};
#pragma unroll
  for (int t = 0; t < 16; ++t) {
    const bool mk = smask[t * 16 + lm] != 0;
#pragma unroll
    for (int r = 0; r < 4; ++r) {
      float v = s[t][r] * 0.125f;
      v = mk ? -1e10f : v;
      s[t][r] = v;
      rmax[r] = fmaxf(rmax[r], v);
    }
  }
#pragma unroll
  for (int off = 1; off < 16; off <<= 1)
#pragma unroll
    for (int r = 0; r < 4; ++r) rmax[r] = fmaxf(rmax[r], __shfl_xor(rmax[r], off));
  float rsum[4] = {0.f, 0.f, 0.f, 0.f};
#pragma unroll
  for (int t = 0; t < 16; ++t)
#pragma unroll
    for (int r = 0; r < 4; ++r) {
      float p = __expf(s[t][r] - rmax[r]);
      s[t][r] = p;
      rsum[r] += p;
    }
#pragma unroll
  for (int off = 1; off < 16; off <<= 1)
#pragma unroll
    for (int r = 0; r < 4; ++r) rsum[r] += __shfl_xor(rsum[r], off);
  float rinv[4];
#pragma unroll
  for (int r = 0; r < 4; ++r) rinv[r] = 1.0f / rsum[r];

  floatx4 o[4];
#pragma unroll
  for (int dt = 0; dt < 4; ++dt) o[dt] = zero4;
  bf16_t* Pw = Ps + w * (16 * 136);
#pragma unroll
  for (int half = 0; half < 2; ++half) {
#pragma unroll
    for (int t = 0; t < 8; ++t) {
      const int tt = half * 8 + t;
#pragma unroll
      for (int r = 0; r < 4; ++r)
        Pw[(lq * 4 + r) * 136 + t * 16 + lm] = (bf16_t)(s[tt][r] * rinv[r]);
    }
    __syncthreads();
#pragma unroll
    for (int ks = 0; ks < 4; ++ks) {
      bf16x8 pa = *(const bf16x8*)(Pw + lm * 136 + ks * 32 + lq * 8);
#pragma unroll
      for (int dt = 0; dt < 4; ++dt) {
        bf16x8 vb = *(const bf16x8*)(Vt + (dt * 16 + lm) * 264 + half * 128 + ks * 32 + lq * 8);
        o[dt] = MFMA16(pa, vb, o[dt]);
      }
    }
    __syncthreads();
  }

#pragma unroll
  for (int dt = 0; dt < 4; ++dt) {
    const int d = dt * 16 + lm;
#pragma unroll
    for (int r = 0; r < 4; ++r) {
      const int token = mrow + lq * 4 + r;
      qkv[(size_t)(b * 4096 + token) * 1024 + 512 + h * 64 + d] = (bf16_t)o[dt][r];
    }
  }
}

// ---------------------------------------------------------------------------
extern "C" void kernel_launch(void* const* d_in, const int* in_sizes, int n_in,
                              void* d_out, int out_size, void* d_ws, size_t ws_size,
                              hipStream_t stream) {
  const float* x   = (const float*)d_in[0];
  const int* mask  = (const int*)d_in[1];
  const float* Wq  = (const float*)d_in[2];
  const float* bq  = (const float*)d_in[3];
  const float* Wk  = (const float*)d_in[4];
  const float* bk  = (const float*)d_in[5];
  const float* Wv  = (const float*)d_in[6];
  const float* bv  = (const float*)d_in[7];
  const float* Wo  = (const float*)d_in[8];
  const float* bo  = (const float*)d_in[9];
  float* out = (float*)d_out;

  // ws: xb 32MB | Wcat 4MB | Wob 2MB | bcat 8KB | vg 16 | qg 16 | kg 16 | qkv 32
  char* ws = (char*)d_ws;
  bf16_t* xb   = (bf16_t*)(ws);
  bf16_t* Wcat = (bf16_t*)(ws + 33554432L);
  bf16_t* Wob  = (bf16_t*)(ws + 37748736L);
  float*  bcat = (float*)(ws + 39845888L);
  bf16_t* vg   = (bf16_t*)(ws + 39854080L);
  bf16_t* qg   = (bf16_t*)(ws + 56631296L);
  bf16_t* kg   = (bf16_t*)(ws + 73408512L);
  bf16_t* qkv  = (bf16_t*)(ws + 90185728L);

  dim3 blk(256);
  cvt_f32_bf16<<<16384, blk, 0, stream>>>(x, xb, 16777216);
  cvt_f32_bf16<<<1024, blk, 0, stream>>>(Wv, Wcat, 1048576);
  cvt_f32_bf16<<<512, blk, 0, stream>>>(Wq + 524288, Wcat + 1048576, 524288);
  cvt_f32_bf16<<<512, blk, 0, stream>>>(Wk + 524288, Wcat + 1572864, 524288);
  cvt_f32_bf16<<<1024, blk, 0, stream>>>(Wo, Wob, 1048576);
  pack_bias<<<8, blk, 0, stream>>>(bv, bq, bk, bcat);

  gemm_proj<<<512, dim3(512), 0, stream>>>(xb, Wcat, bcat, qkv, vg, qg, kg);
  attn_sparse<<<dim3(64, 8, 4), dim3(256), 0, stream>>>(qg, kg, vg, mask, qkv);
  gemm_bt<<<256, dim3(512), 0, stream>>>(qkv, Wob, bo, out, 1024);
}

// Round 3
// 369.014 us; speedup vs baseline: 1.1156x; 1.0322x over previous
//
#include <hip/hip_runtime.h>
#include <stdint.h>

// ---------------------------------------------------------------------------
// Sparse attention, MI355X. f32 I/O, bf16 MFMA internals.
//   0) xb = bf16(x); Wcat = bf16([Wv; Wq[512:]; Wk[512:]]); Wob = bf16(Wo)
//   1) fused proj GEMM: [qkv[:,:512] | vg | qg | kg] = xb @ Wcat^T + bcat
//   2) qkv[:, 512:] = sparse_attention(qg, kg, vg, mask)
//   3) out(f32) = qkv @ Wob^T + bo
//
// GEMMs: m201-style 8-phase schedule, hardened. 256x256 tile, BK=64,
// 512 threads (8 waves 2Mx4N), 2 LDS buffers (128 KiB). Per phase:
//   {ds_read subtile || glds16 stage -> [vmcnt N] ->
//    sched_barrier; s_barrier; s_waitcnt lgkmcnt(0); sched_barrier;
//    setprio(1) 16xMFMA setprio(0);
//    sched_barrier; s_barrier; sched_barrier}
// Main loop (t=0..6) is branch-free; tail (t=7) fully peeled.
// Counted vmcnt: ph2 vmcnt(4) retires prev ph5-8; ph6/ph8 vmcnt(8) retire
// this-iter ph1-2 / ph3-4. Never vmcnt(0) in the main loop.
// Region liveness: each stage region is written >=1 barrier after its last
// reader; its loads retire (counted vmcnt) before its first reader.
// Chunked conflict-free LDS layout; XCD row-band swizzle.
// ---------------------------------------------------------------------------

typedef __bf16 bf16_t;
typedef __bf16 bf16x4 __attribute__((ext_vector_type(4)));
typedef __bf16 bf16x8 __attribute__((ext_vector_type(8)));
typedef float floatx4 __attribute__((ext_vector_type(4)));

#define MFMA16(a, b, c) __builtin_amdgcn_mfma_f32_16x16x32_bf16((a), (b), (c), 0, 0, 0)

// async global->LDS, 16B per lane; LDS dest = wave-uniform base + lane*16
__device__ __forceinline__ void glds16(const bf16_t* g, const bf16_t* lds_base) {
  __builtin_amdgcn_global_load_lds(
      (const __attribute__((address_space(1))) uint32_t*)(uintptr_t)g,
      (__attribute__((address_space(3))) uint32_t*)(uintptr_t)lds_base, 16, 0, 0);
}

#define VMCNT(n)  asm volatile("s_waitcnt vmcnt(" #n ")" ::: "memory")
#define LGKMCNT0  asm volatile("s_waitcnt lgkmcnt(0)" ::: "memory")
#define SBAR      __builtin_amdgcn_s_barrier()
#define SCHED0    __builtin_amdgcn_sched_barrier(0)

// ---------------------------------------------------------------------------
__global__ void cvt_f32_bf16(const float* __restrict__ src, bf16_t* __restrict__ dst, int n) {
  const int i = (blockIdx.x * 256 + threadIdx.x) * 4;
  if (i < n) {
    float4 v = *(const float4*)(src + i);
    bf16x4 d = {(bf16_t)v.x, (bf16_t)v.y, (bf16_t)v.z, (bf16_t)v.w};
    *(bf16x4*)(dst + i) = d;
  }
}

// bcat = [bv(1024); bq[512:](512); bk[512:](512)]  (f32, 2048)
__global__ void pack_bias(const float* __restrict__ bv, const float* __restrict__ bq,
                          const float* __restrict__ bk, float* __restrict__ bcat) {
  const int i = blockIdx.x * 256 + threadIdx.x;  // 2048 threads
  float v;
  if (i < 1024) v = bv[i];
  else if (i < 1536) v = bq[i - 512];
  else v = bk[i - 1024];
  bcat[i] = v;
}

// ---------------------------------------------------------------------------
// 8-phase 256x256 GEMM core. A: (M x 1024) bf16, W: (N x 1024) bf16.
// LDS chunk layout per buffer (2048 chunks of 8 bf16):
//   chunk c = oct*256 + idx  holds Mat[base+idx][tile*64 + oct*8 .. +8]
// Stage region (jk, row-half) = 512 chunks = one glds16 per thread;
// per-wave LDS dest is linear (wave-uniform base + lane*16B).
// K = 1024 -> 16 K-tiles of 64 -> 8 iterations x 2 tiles (buf0 even, buf1 odd).
// ---------------------------------------------------------------------------
#define G8_SETUP(A_, W_, ROW0_, COL0_)                                          \
  __shared__ bf16_t As[2][16384];                                               \
  __shared__ bf16_t Bs[2][16384];                                               \
  const int tid = threadIdx.x;                                                  \
  const int w = tid >> 6, l = tid & 63;                                         \
  const int lq = l >> 4, lm = l & 15;                                           \
  const int wr = (w >> 2) << 7;   /* wave row offset 0/128 */                   \
  const int wc = (w & 3) << 6;    /* wave col offset 0/64/128/192 */            \
  const long row0 = (ROW0_);                                                    \
  const long col0 = (COL0_);                                                    \
  floatx4 acc[8][4];                                                            \
  { floatx4 z = {0.f, 0.f, 0.f, 0.f};                                           \
    _Pragma("unroll") for (int i = 0; i < 8; ++i)                               \
    _Pragma("unroll") for (int j = 0; j < 4; ++j) acc[i][j] = z; }              \
  const int t7 = tid & 127, t8 = tid >> 7;                                      \
  const bf16_t* pAt = (A_) + (row0 + t7) * 1024 + t8 * 8;                       \
  const bf16_t* pBt = (W_) + (col0 + t7) * 1024 + t8 * 8;                       \
  const int sbase = ((((w >> 1) << 8) + ((w & 1) << 6)) << 3);

// stage k-half jk at constant element offset off from the moving pointer
#define G8_ST_A(s, off, jk)                                                     \
  glds16(pAt + (off),          &As[s][0] + ((jk) << 13) + sbase);               \
  glds16(pAt + 131072 + (off), &As[s][0] + ((jk) << 13) + 1024 + sbase);
#define G8_ST_B(s, off, jk)                                                     \
  glds16(pBt + (off),          &Bs[s][0] + ((jk) << 13) + sbase);               \
  glds16(pBt + 131072 + (off), &Bs[s][0] + ((jk) << 13) + 1024 + sbase);

#define G8_READ_B(s, kk)                                                        \
  _Pragma("unroll") for (int nt = 0; nt < 4; ++nt)                              \
    bfr[nt] = *(const bf16x8*)(&Bs[s][0] +                                      \
        (((((kk) * 4 + lq) << 8) + wc + nt * 16 + lm) << 3));

#define G8_READ_A(s, kk, mh)                                                    \
  _Pragma("unroll") for (int i = 0; i < 4; ++i)                                 \
    af[i] = *(const bf16x8*)(&As[s][0] +                                        \
        (((((kk) * 4 + lq) << 8) + wr + (mh) * 64 + i * 16 + lm) << 3));

#define G8_MFMA(mh)                                                             \
  __builtin_amdgcn_s_setprio(1);                                                \
  _Pragma("unroll") for (int i = 0; i < 4; ++i)                                 \
    _Pragma("unroll") for (int nt = 0; nt < 4; ++nt)                            \
      acc[(mh) * 4 + i][nt] = MFMA16(af[i], bfr[nt], acc[(mh) * 4 + i][nt]);    \
  __builtin_amdgcn_s_setprio(0);

// m201-template phase fences (rule #18: sched_barrier(0) after asm waitcnt)
#define PH_PRE   SCHED0; SBAR; LGKMCNT0; SCHED0;
#define PH_POST  SCHED0; SBAR; SCHED0;

// Stage stream (iter t; buf0 = tile 2t, buf1 = tile 2t+1; ptr at tile 2t):
//   ph1: A.k1(2t+1)->buf1 @+96    ph2: B.k1(2t+1)->buf1 @+96   [vmcnt 4]
//   ph3: A.k0(2t+2)->buf0 @+128   ph4: B.k0(2t+2)->buf0 @+128
//   ph5: A.k1(2t+2)->buf0 @+160   ph6: B.k1(2t+2)->buf0 @+160  [vmcnt 8]
//   ph7: A.k0(2t+3)->buf1 @+192   ph8: B.k0(2t+3)->buf1 @+192  [vmcnt 8]
// Retire proof: ph2/vm4 retires prev ph5-8 (buf0.k1(2t) read ph3; buf1.k0
// (2t+1) read ph5); ph6/vm8 retires ph1-2 (buf1.k1 read ph7); ph8/vm8
// retires ph3-4 (buf0.k0(2t+2) read next ph1). Prev ph8/vm8 already retired
// prev ph1-4, so ph1/ph2 reads of buf0.k0(2t) are covered.
#define G8_ITER                                                                 \
    /* ph1 */                                                                   \
    G8_READ_A(0, 0, 0) G8_READ_B(0, 0)                                          \
    G8_ST_A(1, 96, 1)                                                           \
    PH_PRE G8_MFMA(0) PH_POST                                                   \
    /* ph2 */                                                                   \
    G8_READ_A(0, 0, 1)                                                          \
    G8_ST_B(1, 96, 1)                                                           \
    VMCNT(4);                                                                   \
    PH_PRE G8_MFMA(1) PH_POST                                                   \
    /* ph3 */                                                                   \
    G8_READ_A(0, 1, 0) G8_READ_B(0, 1)                                          \
    G8_ST_A(0, 128, 0)                                                          \
    PH_PRE G8_MFMA(0) PH_POST                                                   \
    /* ph4 */                                                                   \
    G8_READ_A(0, 1, 1)                                                          \
    G8_ST_B(0, 128, 0)                                                          \
    PH_PRE G8_MFMA(1) PH_POST                                                   \
    /* ph5 */                                                                   \
    G8_READ_A(1, 0, 0) G8_READ_B(1, 0)                                          \
    G8_ST_A(0, 160, 1)                                                          \
    PH_PRE G8_MFMA(0) PH_POST                                                   \
    /* ph6 */                                                                   \
    G8_READ_A(1, 0, 1)                                                          \
    G8_ST_B(0, 160, 1)                                                          \
    VMCNT(8);                                                                   \
    PH_PRE G8_MFMA(1) PH_POST                                                   \
    /* ph7 */                                                                   \
    G8_READ_A(1, 1, 0) G8_READ_B(1, 1)                                          \
    G8_ST_A(1, 192, 0)                                                          \
    PH_PRE G8_MFMA(0) PH_POST                                                   \
    /* ph8 */                                                                   \
    G8_READ_A(1, 1, 1)                                                          \
    G8_ST_B(1, 192, 0)                                                          \
    VMCNT(8);                                                                   \
    PH_PRE G8_MFMA(1) PH_POST

// Tail (tiles 14 in buf0, 15 in buf1; ptr at tile 14; only t15.k1 to stage).
// Entry outstanding: 8 (last iter ph5-8). ph2/vm4 retires those; ph6/vm0
// drains the tail's own ph1-2 before ph7 reads buf1.k1.
#define G8_TAIL                                                                 \
    G8_READ_A(0, 0, 0) G8_READ_B(0, 0)                                          \
    G8_ST_A(1, 96, 1)                                                           \
    PH_PRE G8_MFMA(0) PH_POST                                                   \
    G8_READ_A(0, 0, 1)                                                          \
    G8_ST_B(1, 96, 1)                                                           \
    VMCNT(4);                                                                   \
    PH_PRE G8_MFMA(1) PH_POST                                                   \
    G8_READ_A(0, 1, 0) G8_READ_B(0, 1)                                          \
    PH_PRE G8_MFMA(0) PH_POST                                                   \
    G8_READ_A(0, 1, 1)                                                          \
    PH_PRE G8_MFMA(1) PH_POST                                                   \
    G8_READ_A(1, 0, 0) G8_READ_B(1, 0)                                          \
    PH_PRE G8_MFMA(0) PH_POST                                                   \
    G8_READ_A(1, 0, 1)                                                          \
    VMCNT(0);                                                                   \
    PH_PRE G8_MFMA(1) PH_POST                                                   \
    G8_READ_A(1, 1, 0) G8_READ_B(1, 1)                                          \
    PH_PRE G8_MFMA(0) PH_POST                                                   \
    G8_READ_A(1, 1, 1)                                                          \
    PH_PRE G8_MFMA(1) PH_POST

// Prologue: tile0 (k0,k1) -> buf0, tile1 k0 -> buf1; drain; barrier.
#define G8_MAIN                                                                 \
  G8_ST_A(0, 0, 0) G8_ST_B(0, 0, 0)                                             \
  G8_ST_A(0, 32, 1) G8_ST_B(0, 32, 1)                                           \
  G8_ST_A(1, 64, 0) G8_ST_B(1, 64, 0)                                           \
  VMCNT(0); SBAR; SCHED0;                                                       \
  bf16x8 af[4], bfr[4];                                                         \
  for (int t = 0; t < 7; ++t) {                                                 \
    G8_ITER                                                                     \
    pAt += 128; pBt += 128;                                                     \
  }                                                                             \
  G8_TAIL

// out-projection GEMM: M=16384, N=1024 -> 64 x 4 tiles = 256 blocks.
// XCD swizzle: xcd = n&7 owns row band [xcd*8, xcd*8+8) x all 4 col tiles.
__global__ __launch_bounds__(512, 2)
void gemm_bt(const bf16_t* __restrict__ A, const bf16_t* __restrict__ W,
             const float* __restrict__ bias, float* __restrict__ C, int ldc) {
  const int n = blockIdx.x, xcd = n & 7, j = n >> 3;  // j in [0,32)
  G8_SETUP(A, W, (long)(xcd * 8 + (j & 7)) * 256, (long)(j >> 3) * 256)
  G8_MAIN
#pragma unroll
  for (int nt = 0; nt < 4; ++nt) {
    const long col = col0 + wc + nt * 16 + lm;
    const float bc = bias[col];
#pragma unroll
    for (int mt = 0; mt < 8; ++mt) {
#pragma unroll
      for (int r = 0; r < 4; ++r) {
        const long row = row0 + wr + mt * 16 + lq * 4 + r;
        C[row * (long)ldc + col] = acc[mt][nt][r] + bc;
      }
    }
  }
}

// fused projection GEMM: M=16384, N=2048 -> 64 x 8 tiles = 512 blocks.
// cols [0,512)->qkv, [512,1024)->vg, [1024,1536)->qg, [1536,2048)->kg
__global__ __launch_bounds__(512, 2)
void gemm_proj(const bf16_t* __restrict__ A, const bf16_t* __restrict__ Wcat,
               const float* __restrict__ bcat, bf16_t* __restrict__ qkv,
               bf16_t* __restrict__ vg, bf16_t* __restrict__ qg,
               bf16_t* __restrict__ kg) {
  const int n = blockIdx.x, xcd = n & 7, j = n >> 3;  // j in [0,64)
  G8_SETUP(A, Wcat, (long)(xcd * 8 + (j & 7)) * 256, (long)(j >> 3) * 256)
  G8_MAIN
  bf16_t* dst; long ld, cofs;
  if (col0 < 512)       { dst = qkv; ld = 1024; cofs = 0; }
  else if (col0 < 1024) { dst = vg;  ld = 512;  cofs = 512; }
  else if (col0 < 1536) { dst = qg;  ld = 512;  cofs = 1024; }
  else                  { dst = kg;  ld = 512;  cofs = 1536; }
#pragma unroll
  for (int nt = 0; nt < 4; ++nt) {
    const long col = col0 + wc + nt * 16 + lm;
    const float bc = bcat[col];
    const long cl = col - cofs;
#pragma unroll
    for (int mt = 0; mt < 8; ++mt) {
#pragma unroll
      for (int r = 0; r < 4; ++r) {
        const long row = row0 + wr + mt * 16 + lq * 4 + r;
        dst[row * ld + cl] = (bf16_t)(acc[mt][nt][r] + bc);
      }
    }
  }
}

// ---------------------------------------------------------------------------
// Sparse attention for global heads. Block = (qt, h, b): 64 query rows,
// 256 selected keys: token(l) = 64*(l>>2) + 32 + 4*h + (l&3).
// ---------------------------------------------------------------------------
__global__ __launch_bounds__(256, 1)
void attn_sparse(const bf16_t* __restrict__ qg, const bf16_t* __restrict__ kg,
                 const bf16_t* __restrict__ vg, const int* __restrict__ mask,
                 bf16_t* __restrict__ qkv) {
  __shared__ bf16_t Ks[16384];        // frag-order: chunk = kq*256 + lkey
  __shared__ bf16_t Vt[64 * 264];     // Vt[d][lkey], row stride 264 (+8 pad)
  __shared__ bf16_t Ps[4 * 16 * 136]; // per-wave P half-tile, stride 136 (+8 pad)
  __shared__ int smask[256];

  const int tid = threadIdx.x;
  const int b = blockIdx.z, h = blockIdx.y, qt = blockIdx.x;

  {
    const int lk = tid;
    const int token = ((lk >> 2) << 6) + 32 + (h << 2) + (lk & 3);
    const size_t rowi = (size_t)(b * 4096 + token);
    const uint4* ksrc = (const uint4*)(kg + rowi * 512 + h * 64);
#pragma unroll
    for (int kq = 0; kq < 8; ++kq)
      *(uint4*)(Ks + (kq * 256 + lk) * 8) = ksrc[kq];
    const bf16_t* vsrc = vg + rowi * 512 + h * 64;
#pragma unroll
    for (int i = 0; i < 8; ++i) {
      bf16x8 vv = *(const bf16x8*)(vsrc + i * 8);
#pragma unroll
      for (int j = 0; j < 8; ++j) Vt[(i * 8 + j) * 264 + lk] = vv[j];
    }
    smask[lk] = mask[b * 4096 + token];
  }
  __syncthreads();

  const int w = tid >> 6, l = tid & 63, lq = l >> 4, lm = l & 15;
  const int mrow = (qt << 6) + (w << 4);

  const bf16_t* qrow = qg + (size_t)(b * 4096 + mrow + lm) * 512 + h * 64 + lq * 8;
  bf16x8 aq0 = *(const bf16x8*)qrow;
  bf16x8 aq1 = *(const bf16x8*)(qrow + 32);

  floatx4 zero4 = {0.f, 0.f, 0.f, 0.f};
  floatx4 s[16];
#pragma unroll
  for (int t = 0; t < 16; ++t) {
    bf16x8 kb0 = *(const bf16x8*)(Ks + (lq * 256 + t * 16 + lm) * 8);
    bf16x8 kb1 = *(const bf16x8*)(Ks + ((4 + lq) * 256 + t * 16 + lm) * 8);
    floatx4 z = zero4;
    z = MFMA16(aq0, kb0, z);
    z = MFMA16(aq1, kb1, z);
    s[t] = z;
  }

  float rmax[4] = {-1e30f, -1e30f, -1e30f, -1e30f};
#pragma unroll
  for (int t = 0; t < 16; ++t) {
    const bool mk = smask[t * 16 + lm] != 0;
#pragma unroll
    for (int r = 0; r < 4; ++r) {
      float v = s[t][r] * 0.125f;
      v = mk ? -1e10f : v;
      s[t][r] = v;
      rmax[r] = fmaxf(rmax[r], v);
    }
  }
#pragma unroll
  for (int off = 1; off < 16; off <<= 1)
#pragma unroll
    for (int r = 0; r < 4; ++r) rmax[r] = fmaxf(rmax[r], __shfl_xor(rmax[r], off));
  float rsum[4] = {0.f, 0.f, 0.f, 0.f};
#pragma unroll
  for (int t = 0; t < 16; ++t)
#pragma unroll
    for (int r = 0; r < 4; ++r) {
      float p = __expf(s[t][r] - rmax[r]);
      s[t][r] = p;
      rsum[r] += p;
    }
#pragma unroll
  for (int off = 1; off < 16; off <<= 1)
#pragma unroll
    for (int r = 0; r < 4; ++r) rsum[r] += __shfl_xor(rsum[r], off);
  float rinv[4];
#pragma unroll
  for (int r = 0; r < 4; ++r) rinv[r] = 1.0f / rsum[r];

  floatx4 o[4];
#pragma unroll
  for (int dt = 0; dt < 4; ++dt) o[dt] = zero4;
  bf16_t* Pw = Ps + w * (16 * 136);
#pragma unroll
  for (int half = 0; half < 2; ++half) {
#pragma unroll
    for (int t = 0; t < 8; ++t) {
      const int tt = half * 8 + t;
#pragma unroll
      for (int r = 0; r < 4; ++r)
        Pw[(lq * 4 + r) * 136 + t * 16 + lm] = (bf16_t)(s[tt][r] * rinv[r]);
    }
    __syncthreads();
#pragma unroll
    for (int ks = 0; ks < 4; ++ks) {
      bf16x8 pa = *(const bf16x8*)(Pw + lm * 136 + ks * 32 + lq * 8);
#pragma unroll
      for (int dt = 0; dt < 4; ++dt) {
        bf16x8 vb = *(const bf16x8*)(Vt + (dt * 16 + lm) * 264 + half * 128 + ks * 32 + lq * 8);
        o[dt] = MFMA16(pa, vb, o[dt]);
      }
    }
    __syncthreads();
  }

#pragma unroll
  for (int dt = 0; dt < 4; ++dt) {
    const int d = dt * 16 + lm;
#pragma unroll
    for (int r = 0; r < 4; ++r) {
      const int token = mrow + lq * 4 + r;
      qkv[(size_t)(b * 4096 + token) * 1024 + 512 + h * 64 + d] = (bf16_t)o[dt][r];
    }
  }
}

// ---------------------------------------------------------------------------
extern "C" void kernel_launch(void* const* d_in, const int* in_sizes, int n_in,
                              void* d_out, int out_size, void* d_ws, size_t ws_size,
                              hipStream_t stream) {
  const float* x   = (const float*)d_in[0];
  const int* mask  = (const int*)d_in[1];
  const float* Wq  = (const float*)d_in[2];
  const float* bq  = (const float*)d_in[3];
  const float* Wk  = (const float*)d_in[4];
  const float* bk  = (const float*)d_in[5];
  const float* Wv  = (const float*)d_in[6];
  const float* bv  = (const float*)d_in[7];
  const float* Wo  = (const float*)d_in[8];
  const float* bo  = (const float*)d_in[9];
  float* out = (float*)d_out;

  // ws: xb 32MB | Wcat 4MB | Wob 2MB | bcat 8KB | vg 16 | qg 16 | kg 16 | qkv 32
  char* ws = (char*)d_ws;
  bf16_t* xb   = (bf16_t*)(ws);
  bf16_t* Wcat = (bf16_t*)(ws + 33554432L);
  bf16_t* Wob  = (bf16_t*)(ws + 37748736L);
  float*  bcat = (float*)(ws + 39845888L);
  bf16_t* vg   = (bf16_t*)(ws + 39854080L);
  bf16_t* qg   = (bf16_t*)(ws + 56631296L);
  bf16_t* kg   = (bf16_t*)(ws + 73408512L);
  bf16_t* qkv  = (bf16_t*)(ws + 90185728L);

  dim3 blk(256);
  cvt_f32_bf16<<<16384, blk, 0, stream>>>(x, xb, 16777216);
  cvt_f32_bf16<<<1024, blk, 0, stream>>>(Wv, Wcat, 1048576);
  cvt_f32_bf16<<<512, blk, 0, stream>>>(Wq + 524288, Wcat + 1048576, 524288);
  cvt_f32_bf16<<<512, blk, 0, stream>>>(Wk + 524288, Wcat + 1572864, 524288);
  cvt_f32_bf16<<<1024, blk, 0, stream>>>(Wo, Wob, 1048576);
  pack_bias<<<8, blk, 0, stream>>>(bv, bq, bk, bcat);

  gemm_proj<<<512, dim3(512), 0, stream>>>(xb, Wcat, bcat, qkv, vg, qg, kg);
  attn_sparse<<<dim3(64, 8, 4), dim3(256), 0, stream>>>(qg, kg, vg, mask, qkv);
  gemm_bt<<<256, dim3(512), 0, stream>>>(qkv, Wob, bo, out, 1024);
}

// Round 5
// 363.882 us; speedup vs baseline: 1.1313x; 1.0141x over previous
//
#include <hip/hip_runtime.h>
#include <stdint.h>

// ---------------------------------------------------------------------------
// Sparse attention, MI355X. f32 I/O, bf16 MFMA internals.
//   0) xb = bf16(x); Wcat = bf16([Wv; Wq[512:]; Wk[512:]]); Wob = bf16(Wo)
//   1) gemm_fused (384 blocks, one dispatch):
//        proj1 (256 blk): all 16384 rows x [Wv-local(512) | Wq-glob(512)]
//                         -> qkv[:, :512], qg
//        proj2 (128 blk): 8192 SELECTED rows (tokens 32..63 mod 64, packed)
//                         x [Wv-glob(512) | Wk-glob(512)] -> vg, kg (packed)
//      (reference only reads gk/gv at tokens ==32..63 mod 64 -> 25% of the
//       projection FLOPs/stage-bytes eliminated)
//   2) qkv[:, 512:] = sparse_attention(qg, kg, vg, mask)  (kg/vg packed rows)
//   3) out(f32) = qkv @ Wob^T + bo
//
// GEMM core: unchanged r3-verified 8-phase schedule (256x256, BK=64, 8 waves,
// 2 LDS buffers, counted vmcnt ph2/ph6/ph8, raw barriers + lgkmcnt fences).
// XCD swizzle = COLUMN ownership: each XCD owns one 256-col B-slice
// (512 KB -> L2-resident) x parity-interleaved row stream.
// HARDENING vs r4: gathered A-row clamped (fault -> wrong-answer conversion;
// no-op if addressing is correct).
// ---------------------------------------------------------------------------

typedef __bf16 bf16_t;
typedef __bf16 bf16x4 __attribute__((ext_vector_type(4)));
typedef __bf16 bf16x8 __attribute__((ext_vector_type(8)));
typedef float floatx4 __attribute__((ext_vector_type(4)));

#define MFMA16(a, b, c) __builtin_amdgcn_mfma_f32_16x16x32_bf16((a), (b), (c), 0, 0, 0)

// async global->LDS, 16B per lane; LDS dest = wave-uniform base + lane*16
__device__ __forceinline__ void glds16(const bf16_t* g, const bf16_t* lds_base) {
  __builtin_amdgcn_global_load_lds(
      (const __attribute__((address_space(1))) uint32_t*)(uintptr_t)g,
      (__attribute__((address_space(3))) uint32_t*)(uintptr_t)lds_base, 16, 0, 0);
}

#define VMCNT(n)  asm volatile("s_waitcnt vmcnt(" #n ")" ::: "memory")
#define LGKMCNT0  asm volatile("s_waitcnt lgkmcnt(0)" ::: "memory")
#define SBAR      __builtin_amdgcn_s_barrier()
#define SCHED0    __builtin_amdgcn_sched_barrier(0)

// ---------------------------------------------------------------------------
__global__ void cvt_f32_bf16(const float* __restrict__ src, bf16_t* __restrict__ dst, int n) {
  const int i = (blockIdx.x * 256 + threadIdx.x) * 4;
  if (i < n) {
    float4 v = *(const float4*)(src + i);
    bf16x4 d = {(bf16_t)v.x, (bf16_t)v.y, (bf16_t)v.z, (bf16_t)v.w};
    *(bf16x4*)(dst + i) = d;
  }
}

// bcat = [bv(1024); bq[512:](512); bk[512:](512)]  (f32, 2048)
__global__ void pack_bias(const float* __restrict__ bv, const float* __restrict__ bq,
                          const float* __restrict__ bk, float* __restrict__ bcat) {
  const int i = blockIdx.x * 256 + threadIdx.x;  // 2048 threads
  float v;
  if (i < 1024) v = bv[i];
  else if (i < 1536) v = bq[i - 512];
  else v = bk[i - 1024];
  bcat[i] = v;
}

// ---------------------------------------------------------------------------
// 8-phase 256x256 GEMM core (r3-verified). LDS chunk layout per buffer:
//   chunk c = oct*256 + idx  holds Mat[base+idx][tile*64 + oct*8 .. +8]
// Requires in scope: pAt, pBt (moving, +=128/iter), aoff2 (A second-half
// element offset: +128 GEMM rows), sbase, acc, and the id vars from G8_DECL.
// ---------------------------------------------------------------------------
#define G8_DECL                                                                 \
  __shared__ bf16_t As[2][16384];                                               \
  __shared__ bf16_t Bs[2][16384];                                               \
  const int tid = threadIdx.x;                                                  \
  const int w = tid >> 6, l = tid & 63;                                         \
  const int lq = l >> 4, lm = l & 15;                                           \
  const int wr = (w >> 2) << 7;   /* wave row offset 0/128 */                   \
  const int wc = (w & 3) << 6;    /* wave col offset 0/64/128/192 */            \
  floatx4 acc[8][4];                                                            \
  { floatx4 z = {0.f, 0.f, 0.f, 0.f};                                           \
    _Pragma("unroll") for (int i = 0; i < 8; ++i)                               \
    _Pragma("unroll") for (int j = 0; j < 4; ++j) acc[i][j] = z; }              \
  const int t7 = tid & 127, t8 = tid >> 7;                                      \
  const int sbase = ((((w >> 1) << 8) + ((w & 1) << 6)) << 3);

#define G8_ST_A(s, off, jk)                                                     \
  glds16(pAt + (off),         &As[s][0] + ((jk) << 13) + sbase);                \
  glds16(pAt + aoff2 + (off), &As[s][0] + ((jk) << 13) + 1024 + sbase);
#define G8_ST_B(s, off, jk)                                                     \
  glds16(pBt + (off),          &Bs[s][0] + ((jk) << 13) + sbase);               \
  glds16(pBt + 131072 + (off), &Bs[s][0] + ((jk) << 13) + 1024 + sbase);

#define G8_READ_B(s, kk)                                                        \
  _Pragma("unroll") for (int nt = 0; nt < 4; ++nt)                              \
    bfr[nt] = *(const bf16x8*)(&Bs[s][0] +                                      \
        (((((kk) * 4 + lq) << 8) + wc + nt * 16 + lm) << 3));

#define G8_READ_A(s, kk, mh)                                                    \
  _Pragma("unroll") for (int i = 0; i < 4; ++i)                                 \
    af[i] = *(const bf16x8*)(&As[s][0] +                                        \
        (((((kk) * 4 + lq) << 8) + wr + (mh) * 64 + i * 16 + lm) << 3));

#define G8_MFMA(mh)                                                             \
  __builtin_amdgcn_s_setprio(1);                                                \
  _Pragma("unroll") for (int i = 0; i < 4; ++i)                                 \
    _Pragma("unroll") for (int nt = 0; nt < 4; ++nt)                            \
      acc[(mh) * 4 + i][nt] = MFMA16(af[i], bfr[nt], acc[(mh) * 4 + i][nt]);    \
  __builtin_amdgcn_s_setprio(0);

#define PH_PRE   SCHED0; SBAR; LGKMCNT0; SCHED0;
#define PH_POST  SCHED0; SBAR; SCHED0;

// Stage/retire ledger identical to r3 (verified): vmcnt(4)@ph2 retires prev
// ph5-8; vmcnt(8)@ph6 retires ph1-2; vmcnt(8)@ph8 retires ph3-4. Never 0 in
// the main loop; tail peeled with vmcnt(4)/vmcnt(0).
#define G8_ITER                                                                 \
    G8_READ_A(0, 0, 0) G8_READ_B(0, 0)                                          \
    G8_ST_A(1, 96, 1)                                                           \
    PH_PRE G8_MFMA(0) PH_POST                                                   \
    G8_READ_A(0, 0, 1)                                                          \
    G8_ST_B(1, 96, 1)                                                           \
    VMCNT(4);                                                                   \
    PH_PRE G8_MFMA(1) PH_POST                                                   \
    G8_READ_A(0, 1, 0) G8_READ_B(0, 1)                                          \
    G8_ST_A(0, 128, 0)                                                          \
    PH_PRE G8_MFMA(0) PH_POST                                                   \
    G8_READ_A(0, 1, 1)                                                          \
    G8_ST_B(0, 128, 0)                                                          \
    PH_PRE G8_MFMA(1) PH_POST                                                   \
    G8_READ_A(1, 0, 0) G8_READ_B(1, 0)                                          \
    G8_ST_A(0, 160, 1)                                                          \
    PH_PRE G8_MFMA(0) PH_POST                                                   \
    G8_READ_A(1, 0, 1)                                                          \
    G8_ST_B(0, 160, 1)                                                          \
    VMCNT(8);                                                                   \
    PH_PRE G8_MFMA(1) PH_POST                                                   \
    G8_READ_A(1, 1, 0) G8_READ_B(1, 1)                                          \
    G8_ST_A(1, 192, 0)                                                          \
    PH_PRE G8_MFMA(0) PH_POST                                                   \
    G8_READ_A(1, 1, 1)                                                          \
    G8_ST_B(1, 192, 0)                                                          \
    VMCNT(8);                                                                   \
    PH_PRE G8_MFMA(1) PH_POST

#define G8_TAIL                                                                 \
    G8_READ_A(0, 0, 0) G8_READ_B(0, 0)                                          \
    G8_ST_A(1, 96, 1)                                                           \
    PH_PRE G8_MFMA(0) PH_POST                                                   \
    G8_READ_A(0, 0, 1)                                                          \
    G8_ST_B(1, 96, 1)                                                           \
    VMCNT(4);                                                                   \
    PH_PRE G8_MFMA(1) PH_POST                                                   \
    G8_READ_A(0, 1, 0) G8_READ_B(0, 1)                                          \
    PH_PRE G8_MFMA(0) PH_POST                                                   \
    G8_READ_A(0, 1, 1)                                                          \
    PH_PRE G8_MFMA(1) PH_POST                                                   \
    G8_READ_A(1, 0, 0) G8_READ_B(1, 0)                                          \
    PH_PRE G8_MFMA(0) PH_POST                                                   \
    G8_READ_A(1, 0, 1)                                                          \
    VMCNT(0);                                                                   \
    PH_PRE G8_MFMA(1) PH_POST                                                   \
    G8_READ_A(1, 1, 0) G8_READ_B(1, 1)                                          \
    PH_PRE G8_MFMA(0) PH_POST                                                   \
    G8_READ_A(1, 1, 1)                                                          \
    PH_PRE G8_MFMA(1) PH_POST

#define G8_MAIN                                                                 \
  G8_ST_A(0, 0, 0) G8_ST_B(0, 0, 0)                                             \
  G8_ST_A(0, 32, 1) G8_ST_B(0, 32, 1)                                           \
  G8_ST_A(1, 64, 0) G8_ST_B(1, 64, 0)                                           \
  VMCNT(0); SBAR; SCHED0;                                                       \
  bf16x8 af[4], bfr[4];                                                         \
  for (int t = 0; t < 7; ++t) {                                                 \
    G8_ITER                                                                     \
    pAt += 128; pBt += 128;                                                     \
  }                                                                             \
  G8_TAIL

// ---------------------------------------------------------------------------
// Fused projection: 384 blocks.
//  n < 256  (proj1): all rows. xcd=n&7 OWNS col-tile ct=xcd>>1 (B-slice
//    256x1024x2B = 512KB, L2-resident); row-tile rt = (n>>3)*2 + (xcd&1).
//    cols: ct<2 -> Wv-local [0,512) -> qkv ; ct>=2 -> Wq [1024,1536) -> qg.
//  n >= 256 (proj2): packed selected rows (token%64 in [32,64)).
//    m2=n-256; xcd=m2&7; ct=xcd>>1; rt2=(m2>>3)*2+(xcd&1) in [0,32).
//    packed row r -> global A row = ((r>>5)<<6)+32+(r&31) (linear in 32-row
//    runs; +128 packed rows = +256 global rows -> aoff2 = 262144).
//    r clamped to 8063 (defensive; max legit = 7936+127 = 8063).
//    cols: ct<2 -> Wv-glob [512,1024) -> vg ; ct>=2 -> Wk [1536,2048) -> kg.
// ---------------------------------------------------------------------------
__global__ __launch_bounds__(512, 2)
void gemm_fused(const bf16_t* __restrict__ A, const bf16_t* __restrict__ Wcat,
                const float* __restrict__ bcat, bf16_t* __restrict__ qkv,
                bf16_t* __restrict__ vg, bf16_t* __restrict__ qg,
                bf16_t* __restrict__ kg) {
  G8_DECL
  const int n = blockIdx.x;
  long row0, col0;
  int aoff2;
  const bf16_t* pAt;
  if (n < 256) {
    const int xcd = n & 7;
    const int ct = xcd >> 1;
    row0 = (long)(((n >> 3) << 1) | (xcd & 1)) * 256;   // [0,16384)
    col0 = ct * 256 + (ct >= 2 ? 512 : 0);
    aoff2 = 131072;
    pAt = A + (row0 + t7) * 1024 + t8 * 8;
  } else {
    const int m2 = n - 256;
    const int xcd = m2 & 7;
    const int ct = xcd >> 1;
    row0 = (long)(((m2 >> 3) << 1) | (xcd & 1)) * 256;  // [0,8192)
    col0 = (ct < 2) ? (512 + ct * 256) : (1536 + (ct - 2) * 256);
    aoff2 = 262144;
    long r = row0 + t7;
    if (r > 8063) r = 8063;                              // defensive clamp
    const long g = ((r >> 5) << 6) + 32 + (r & 31);      // gathered global row
    pAt = A + g * 1024 + t8 * 8;
  }
  const bf16_t* pBt = Wcat + (col0 + t7) * 1024 + t8 * 8;
  G8_MAIN
  bf16_t* dst; long ld, cofs;
  if (col0 < 512)       { dst = qkv; ld = 1024; cofs = 0; }
  else if (col0 < 1024) { dst = vg;  ld = 512;  cofs = 512; }
  else if (col0 < 1536) { dst = qg;  ld = 512;  cofs = 1024; }
  else                  { dst = kg;  ld = 512;  cofs = 1536; }
#pragma unroll
  for (int nt = 0; nt < 4; ++nt) {
    const long col = col0 + wc + nt * 16 + lm;
    const float bc = bcat[col];
    const long cl = col - cofs;
#pragma unroll
    for (int mt = 0; mt < 8; ++mt) {
#pragma unroll
      for (int r = 0; r < 4; ++r) {
        const long row = row0 + wr + mt * 16 + lq * 4 + r;
        dst[row * ld + cl] = (bf16_t)(acc[mt][nt][r] + bc);
      }
    }
  }
}

// out-projection GEMM: M=16384, N=1024 -> 256 blocks, col-ownership swizzle
// (Wob slice 512KB L2-resident per XCD).
__global__ __launch_bounds__(512, 2)
void gemm_bt(const bf16_t* __restrict__ A, const bf16_t* __restrict__ W,
             const float* __restrict__ bias, float* __restrict__ C, int ldc) {
  G8_DECL
  const int n = blockIdx.x, xcd = n & 7;
  const long row0 = (long)(((n >> 3) << 1) | (xcd & 1)) * 256;  // [0,16384)
  const long col0 = (long)(xcd >> 1) * 256;                      // [0,1024)
  const int aoff2 = 131072;
  const bf16_t* pAt = A + (row0 + t7) * 1024 + t8 * 8;
  const bf16_t* pBt = W + (col0 + t7) * 1024 + t8 * 8;
  G8_MAIN
#pragma unroll
  for (int nt = 0; nt < 4; ++nt) {
    const long col = col0 + wc + nt * 16 + lm;
    const float bc = bias[col];
#pragma unroll
    for (int mt = 0; mt < 8; ++mt) {
#pragma unroll
      for (int r = 0; r < 4; ++r) {
        const long row = row0 + wr + mt * 16 + lq * 4 + r;
        C[row * (long)ldc + col] = acc[mt][nt][r] + bc;
      }
    }
  }
}

// ---------------------------------------------------------------------------
// Sparse attention for global heads. Block = (qt, h, b): 64 query rows,
// 256 selected keys: token(l) = 64*(l>>2) + 32 + 4*h + (l&3).
// kg/vg are PACKED: packed row = 32*(token>>6) + (token&63) - 32
//                              = ((l>>2)<<5) + 4*h + (l&3), 2048 rows/batch.
// ---------------------------------------------------------------------------
__global__ __launch_bounds__(256, 1)
void attn_sparse(const bf16_t* __restrict__ qg, const bf16_t* __restrict__ kg,
                 const bf16_t* __restrict__ vg, const int* __restrict__ mask,
                 bf16_t* __restrict__ qkv) {
  __shared__ bf16_t Ks[16384];        // frag-order: chunk = kq*256 + lkey
  __shared__ bf16_t Vt[64 * 264];     // Vt[d][lkey], row stride 264 (+8 pad)
  __shared__ bf16_t Ps[4 * 16 * 136]; // per-wave P half-tile, stride 136 (+8 pad)
  __shared__ int smask[256];

  const int tid = threadIdx.x;
  const int b = blockIdx.z, h = blockIdx.y, qt = blockIdx.x;

  {
    const int lk = tid;
    const int token = ((lk >> 2) << 6) + 32 + (h << 2) + (lk & 3);
    const int selrow = ((lk >> 2) << 5) + (h << 2) + (lk & 3);
    const size_t rowi = (size_t)(b * 2048 + selrow);
    const uint4* ksrc = (const uint4*)(kg + rowi * 512 + h * 64);
#pragma unroll
    for (int kq = 0; kq < 8; ++kq)
      *(uint4*)(Ks + (kq * 256 + lk) * 8) = ksrc[kq];
    const bf16_t* vsrc = vg + rowi * 512 + h * 64;
#pragma unroll
    for (int i = 0; i < 8; ++i) {
      bf16x8 vv = *(const bf16x8*)(vsrc + i * 8);
#pragma unroll
      for (int j = 0; j < 8; ++j) Vt[(i * 8 + j) * 264 + lk] = vv[j];
    }
    smask[lk] = mask[b * 4096 + token];
  }
  __syncthreads();

  const int w = tid >> 6, l = tid & 63, lq = l >> 4, lm = l & 15;
  const int mrow = (qt << 6) + (w << 4);

  const bf16_t* qrow = qg + (size_t)(b * 4096 + mrow + lm) * 512 + h * 64 + lq * 8;
  bf16x8 aq0 = *(const bf16x8*)qrow;
  bf16x8 aq1 = *(const bf16x8*)(qrow + 32);

  floatx4 zero4 = {0.f, 0.f, 0.f, 0.f};
  floatx4 s[16];
#pragma unroll
  for (int t = 0; t < 16; ++t) {
    bf16x8 kb0 = *(const bf16x8*)(Ks + (lq * 256 + t * 16 + lm) * 8);
    bf16x8 kb1 = *(const bf16x8*)(Ks + ((4 + lq) * 256 + t * 16 + lm) * 8);
    floatx4 z = zero4;
    z = MFMA16(aq0, kb0, z);
    z = MFMA16(aq1, kb1, z);
    s[t] = z;
  }

  float rmax[4] = {-1e30f, -1e30f, -1e30f, -1e30f};
#pragma unroll
  for (int t = 0; t < 16; ++t) {
    const bool mk = smask[t * 16 + lm] != 0;
#pragma unroll
    for (int r = 0; r < 4; ++r) {
      float v = s[t][r] * 0.125f;
      v = mk ? -1e10f : v;
      s[t][r] = v;
      rmax[r] = fmaxf(rmax[r], v);
    }
  }
#pragma unroll
  for (int off = 1; off < 16; off <<= 1)
#pragma unroll
    for (int r = 0; r < 4; ++r) rmax[r] = fmaxf(rmax[r], __shfl_xor(rmax[r], off));
  float rsum[4] = {0.f, 0.f, 0.f, 0.f};
#pragma unroll
  for (int t = 0; t < 16; ++t)
#pragma unroll
    for (int r = 0; r < 4; ++r) {
      float p = __expf(s[t][r] - rmax[r]);
      s[t][r] = p;
      rsum[r] += p;
    }
#pragma unroll
  for (int off = 1; off < 16; off <<= 1)
#pragma unroll
    for (int r = 0; r < 4; ++r) rsum[r] += __shfl_xor(rsum[r], off);
  float rinv[4];
#pragma unroll
  for (int r = 0; r < 4; ++r) rinv[r] = 1.0f / rsum[r];

  floatx4 o[4];
#pragma unroll
  for (int dt = 0; dt < 4; ++dt) o[dt] = zero4;
  bf16_t* Pw = Ps + w * (16 * 136);
#pragma unroll
  for (int half = 0; half < 2; ++half) {
#pragma unroll
    for (int t = 0; t < 8; ++t) {
      const int tt = half * 8 + t;
#pragma unroll
      for (int r = 0; r < 4; ++r)
        Pw[(lq * 4 + r) * 136 + t * 16 + lm] = (bf16_t)(s[tt][r] * rinv[r]);
    }
    __syncthreads();
#pragma unroll
    for (int ks = 0; ks < 4; ++ks) {
      bf16x8 pa = *(const bf16x8*)(Pw + lm * 136 + ks * 32 + lq * 8);
#pragma unroll
      for (int dt = 0; dt < 4; ++dt) {
        bf16x8 vb = *(const bf16x8*)(Vt + (dt * 16 + lm) * 264 + half * 128 + ks * 32 + lq * 8);
        o[dt] = MFMA16(pa, vb, o[dt]);
      }
    }
    __syncthreads();
  }

#pragma unroll
  for (int dt = 0; dt < 4; ++dt) {
    const int d = dt * 16 + lm;
#pragma unroll
    for (int r = 0; r < 4; ++r) {
      const int token = mrow + lq * 4 + r;
      qkv[(size_t)(b * 4096 + token) * 1024 + 512 + h * 64 + d] = (bf16_t)o[dt][r];
    }
  }
}

// ---------------------------------------------------------------------------
extern "C" void kernel_launch(void* const* d_in, const int* in_sizes, int n_in,
                              void* d_out, int out_size, void* d_ws, size_t ws_size,
                              hipStream_t stream) {
  const float* x   = (const float*)d_in[0];
  const int* mask  = (const int*)d_in[1];
  const float* Wq  = (const float*)d_in[2];
  const float* bq  = (const float*)d_in[3];
  const float* Wk  = (const float*)d_in[4];
  const float* bk  = (const float*)d_in[5];
  const float* Wv  = (const float*)d_in[6];
  const float* bv  = (const float*)d_in[7];
  const float* Wo  = (const float*)d_in[8];
  const float* bo  = (const float*)d_in[9];
  float* out = (float*)d_out;

  // ws: xb 32MB | Wcat 4MB | Wob 2MB | bcat 8KB | vg | qg | kg | qkv
  char* ws = (char*)d_ws;
  bf16_t* xb   = (bf16_t*)(ws);
  bf16_t* Wcat = (bf16_t*)(ws + 33554432L);
  bf16_t* Wob  = (bf16_t*)(ws + 37748736L);
  float*  bcat = (float*)(ws + 39845888L);
  bf16_t* vg   = (bf16_t*)(ws + 39854080L);   // packed 4x2048x512 bf16 = 8MB
  bf16_t* qg   = (bf16_t*)(ws + 56631296L);   // full 16384x512 bf16 = 16MB
  bf16_t* kg   = (bf16_t*)(ws + 73408512L);   // packed 4x2048x512 bf16 = 8MB
  bf16_t* qkv  = (bf16_t*)(ws + 90185728L);   // 16384x1024 bf16 = 32MB

  dim3 blk(256);
  cvt_f32_bf16<<<16384, blk, 0, stream>>>(x, xb, 16777216);
  cvt_f32_bf16<<<1024, blk, 0, stream>>>(Wv, Wcat, 1048576);
  cvt_f32_bf16<<<512, blk, 0, stream>>>(Wq + 524288, Wcat + 1048576, 524288);
  cvt_f32_bf16<<<512, blk, 0, stream>>>(Wk + 524288, Wcat + 1572864, 524288);
  cvt_f32_bf16<<<1024, blk, 0, stream>>>(Wo, Wob, 1048576);
  pack_bias<<<8, blk, 0, stream>>>(bv, bq, bk, bcat);

  gemm_fused<<<384, dim3(512), 0, stream>>>(xb, Wcat, bcat, qkv, vg, qg, kg);
  attn_sparse<<<dim3(64, 8, 4), dim3(256), 0, stream>>>(qg, kg, vg, mask, qkv);
  gemm_bt<<<256, dim3(512), 0, stream>>>(qkv, Wob, bo, out, 1024);
}

// Round 6
// 349.191 us; speedup vs baseline: 1.1789x; 1.0421x over previous
//
#include <hip/hip_runtime.h>
#include <stdint.h>

// ---------------------------------------------------------------------------
// Sparse attention, MI355X. f32 I/O, bf16 MFMA internals.
//   0) xb = bf16(x); Wcat = bf16([Wv; Wq[512:]; Wk[512:]]); Wob = bf16(Wo)
//   1) gemm_fused (384 blocks, one dispatch):
//        proj1 (256 blk): all 16384 rows x [Wv-local(512) | Wq-glob(512)]
//                         -> qkv[:, :512], qg
//        proj2 (128 blk): 8192 SELECTED rows (tokens 32..63 mod 64, packed)
//                         x [Wv-glob(512) | Wk-glob(512)] -> vg, kg (packed)
//      (reference only reads gk/gv at tokens ==32..63 mod 64 -> 25% of the
//       projection FLOPs/stage-bytes eliminated)
//   2) qkv[:, 512:] = sparse_attention(qg, kg, vg, mask)  (kg/vg packed rows)
//   3) out(f32) = qkv @ Wob^T + bo
//
// GEMM core: r3-verified 8-phase schedule (256x256, BK=64, 8 waves, 2 LDS
// buffers, counted vmcnt ph2/ph6/ph8, raw barriers + lgkmcnt fences).
// XCD swizzle: ROW-BAND ownership (r3-proven: 64.7us/round, FETCH 49MB;
// r5's col-ownership doubled FETCH (A streamed by 4 XCDs) and cost 11%
// per-round -> reverted). Per XCD: A-band 4MB + B 2MB, best L2 fit yet.
// ---------------------------------------------------------------------------

typedef __bf16 bf16_t;
typedef __bf16 bf16x4 __attribute__((ext_vector_type(4)));
typedef __bf16 bf16x8 __attribute__((ext_vector_type(8)));
typedef float floatx4 __attribute__((ext_vector_type(4)));

#define MFMA16(a, b, c) __builtin_amdgcn_mfma_f32_16x16x32_bf16((a), (b), (c), 0, 0, 0)

// async global->LDS, 16B per lane; LDS dest = wave-uniform base + lane*16
__device__ __forceinline__ void glds16(const bf16_t* g, const bf16_t* lds_base) {
  __builtin_amdgcn_global_load_lds(
      (const __attribute__((address_space(1))) uint32_t*)(uintptr_t)g,
      (__attribute__((address_space(3))) uint32_t*)(uintptr_t)lds_base, 16, 0, 0);
}

#define VMCNT(n)  asm volatile("s_waitcnt vmcnt(" #n ")" ::: "memory")
#define LGKMCNT0  asm volatile("s_waitcnt lgkmcnt(0)" ::: "memory")
#define SBAR      __builtin_amdgcn_s_barrier()
#define SCHED0    __builtin_amdgcn_sched_barrier(0)

// ---------------------------------------------------------------------------
__global__ void cvt_f32_bf16(const float* __restrict__ src, bf16_t* __restrict__ dst, int n) {
  const int i = (blockIdx.x * 256 + threadIdx.x) * 4;
  if (i < n) {
    float4 v = *(const float4*)(src + i);
    bf16x4 d = {(bf16_t)v.x, (bf16_t)v.y, (bf16_t)v.z, (bf16_t)v.w};
    *(bf16x4*)(dst + i) = d;
  }
}

// bcat = [bv(1024); bq[512:](512); bk[512:](512)]  (f32, 2048)
__global__ void pack_bias(const float* __restrict__ bv, const float* __restrict__ bq,
                          const float* __restrict__ bk, float* __restrict__ bcat) {
  const int i = blockIdx.x * 256 + threadIdx.x;  // 2048 threads
  float v;
  if (i < 1024) v = bv[i];
  else if (i < 1536) v = bq[i - 512];
  else v = bk[i - 1024];
  bcat[i] = v;
}

// ---------------------------------------------------------------------------
// 8-phase 256x256 GEMM core (r3-verified). LDS chunk layout per buffer:
//   chunk c = oct*256 + idx  holds Mat[base+idx][tile*64 + oct*8 .. +8]
// Requires in scope: pAt, pBt (moving, +=128/iter), aoff2 (A second-half
// element offset: +128 GEMM rows), sbase, acc, and the id vars from G8_DECL.
// ---------------------------------------------------------------------------
#define G8_DECL                                                                 \
  __shared__ bf16_t As[2][16384];                                               \
  __shared__ bf16_t Bs[2][16384];                                               \
  const int tid = threadIdx.x;                                                  \
  const int w = tid >> 6, l = tid & 63;                                         \
  const int lq = l >> 4, lm = l & 15;                                           \
  const int wr = (w >> 2) << 7;   /* wave row offset 0/128 */                   \
  const int wc = (w & 3) << 6;    /* wave col offset 0/64/128/192 */            \
  floatx4 acc[8][4];                                                            \
  { floatx4 z = {0.f, 0.f, 0.f, 0.f};                                           \
    _Pragma("unroll") for (int i = 0; i < 8; ++i)                               \
    _Pragma("unroll") for (int j = 0; j < 4; ++j) acc[i][j] = z; }              \
  const int t7 = tid & 127, t8 = tid >> 7;                                      \
  const int sbase = ((((w >> 1) << 8) + ((w & 1) << 6)) << 3);

#define G8_ST_A(s, off, jk)                                                     \
  glds16(pAt + (off),         &As[s][0] + ((jk) << 13) + sbase);                \
  glds16(pAt + aoff2 + (off), &As[s][0] + ((jk) << 13) + 1024 + sbase);
#define G8_ST_B(s, off, jk)                                                     \
  glds16(pBt + (off),          &Bs[s][0] + ((jk) << 13) + sbase);               \
  glds16(pBt + 131072 + (off), &Bs[s][0] + ((jk) << 13) + 1024 + sbase);

#define G8_READ_B(s, kk)                                                        \
  _Pragma("unroll") for (int nt = 0; nt < 4; ++nt)                              \
    bfr[nt] = *(const bf16x8*)(&Bs[s][0] +                                      \
        (((((kk) * 4 + lq) << 8) + wc + nt * 16 + lm) << 3));

#define G8_READ_A(s, kk, mh)                                                    \
  _Pragma("unroll") for (int i = 0; i < 4; ++i)                                 \
    af[i] = *(const bf16x8*)(&As[s][0] +                                        \
        (((((kk) * 4 + lq) << 8) + wr + (mh) * 64 + i * 16 + lm) << 3));

#define G8_MFMA(mh)                                                             \
  __builtin_amdgcn_s_setprio(1);                                                \
  _Pragma("unroll") for (int i = 0; i < 4; ++i)                                 \
    _Pragma("unroll") for (int nt = 0; nt < 4; ++nt)                            \
      acc[(mh) * 4 + i][nt] = MFMA16(af[i], bfr[nt], acc[(mh) * 4 + i][nt]);    \
  __builtin_amdgcn_s_setprio(0);

#define PH_PRE   SCHED0; SBAR; LGKMCNT0; SCHED0;
#define PH_POST  SCHED0; SBAR; SCHED0;

// Stage/retire ledger identical to r3 (verified): vmcnt(4)@ph2 retires prev
// ph5-8; vmcnt(8)@ph6 retires ph1-2; vmcnt(8)@ph8 retires ph3-4. Never 0 in
// the main loop; tail peeled with vmcnt(4)/vmcnt(0).
#define G8_ITER                                                                 \
    G8_READ_A(0, 0, 0) G8_READ_B(0, 0)                                          \
    G8_ST_A(1, 96, 1)                                                           \
    PH_PRE G8_MFMA(0) PH_POST                                                   \
    G8_READ_A(0, 0, 1)                                                          \
    G8_ST_B(1, 96, 1)                                                           \
    VMCNT(4);                                                                   \
    PH_PRE G8_MFMA(1) PH_POST                                                   \
    G8_READ_A(0, 1, 0) G8_READ_B(0, 1)                                          \
    G8_ST_A(0, 128, 0)                                                          \
    PH_PRE G8_MFMA(0) PH_POST                                                   \
    G8_READ_A(0, 1, 1)                                                          \
    G8_ST_B(0, 128, 0)                                                          \
    PH_PRE G8_MFMA(1) PH_POST                                                   \
    G8_READ_A(1, 0, 0) G8_READ_B(1, 0)                                          \
    G8_ST_A(0, 160, 1)                                                          \
    PH_PRE G8_MFMA(0) PH_POST                                                   \
    G8_READ_A(1, 0, 1)                                                          \
    G8_ST_B(0, 160, 1)                                                          \
    VMCNT(8);                                                                   \
    PH_PRE G8_MFMA(1) PH_POST                                                   \
    G8_READ_A(1, 1, 0) G8_READ_B(1, 1)                                          \
    G8_ST_A(1, 192, 0)                                                          \
    PH_PRE G8_MFMA(0) PH_POST                                                   \
    G8_READ_A(1, 1, 1)                                                          \
    G8_ST_B(1, 192, 0)                                                          \
    VMCNT(8);                                                                   \
    PH_PRE G8_MFMA(1) PH_POST

#define G8_TAIL                                                                 \
    G8_READ_A(0, 0, 0) G8_READ_B(0, 0)                                          \
    G8_ST_A(1, 96, 1)                                                           \
    PH_PRE G8_MFMA(0) PH_POST                                                   \
    G8_READ_A(0, 0, 1)                                                          \
    G8_ST_B(1, 96, 1)                                                           \
    VMCNT(4);                                                                   \
    PH_PRE G8_MFMA(1) PH_POST                                                   \
    G8_READ_A(0, 1, 0) G8_READ_B(0, 1)                                          \
    PH_PRE G8_MFMA(0) PH_POST                                                   \
    G8_READ_A(0, 1, 1)                                                          \
    PH_PRE G8_MFMA(1) PH_POST                                                   \
    G8_READ_A(1, 0, 0) G8_READ_B(1, 0)                                          \
    PH_PRE G8_MFMA(0) PH_POST                                                   \
    G8_READ_A(1, 0, 1)                                                          \
    VMCNT(0);                                                                   \
    PH_PRE G8_MFMA(1) PH_POST                                                   \
    G8_READ_A(1, 1, 0) G8_READ_B(1, 1)                                          \
    PH_PRE G8_MFMA(0) PH_POST                                                   \
    G8_READ_A(1, 1, 1)                                                          \
    PH_PRE G8_MFMA(1) PH_POST

#define G8_MAIN                                                                 \
  G8_ST_A(0, 0, 0) G8_ST_B(0, 0, 0)                                             \
  G8_ST_A(0, 32, 1) G8_ST_B(0, 32, 1)                                           \
  G8_ST_A(1, 64, 0) G8_ST_B(1, 64, 0)                                           \
  VMCNT(0); SBAR; SCHED0;                                                       \
  bf16x8 af[4], bfr[4];                                                         \
  for (int t = 0; t < 7; ++t) {                                                 \
    G8_ITER                                                                     \
    pAt += 128; pBt += 128;                                                     \
  }                                                                             \
  G8_TAIL

// ---------------------------------------------------------------------------
// Fused projection: 384 blocks, ROW-BAND XCD swizzle.
//  n < 256  (proj1): all 16384 rows. xcd=n&7; j=n>>3 in [0,32);
//    row0 = (xcd*8 + (j&7))*256  (A-band 2048 rows = 4MB, L2-resident);
//    ct = j>>3 in [0,4); cols: ct<2 -> Wv-local [0,512) -> qkv ;
//                              ct>=2 -> Wq [1024,1536) -> qg.
//  n >= 256 (proj2): 8192 packed selected rows (token%64 in [32,64)).
//    m2=n-256; xcd=m2&7; j=m2>>3 in [0,16); row0=(xcd*4+(j&3))*256
//    (A-band 1024 packed rows -> 2048 global rows, 4MB);
//    ct = j>>2; cols: ct<2 -> Wv-glob [512,1024) -> vg ;
//                     ct>=2 -> Wk [1536,2048) -> kg.
//    packed row r -> global A row = ((r>>5)<<6)+32+(r&31) (linear in 32-row
//    runs; +128 packed rows = +256 global rows -> aoff2 = 262144).
//    r clamped to 8063 (defensive; max legit = 7936+127 = 8063).
// ---------------------------------------------------------------------------
__global__ __launch_bounds__(512, 2)
void gemm_fused(const bf16_t* __restrict__ A, const bf16_t* __restrict__ Wcat,
                const float* __restrict__ bcat, bf16_t* __restrict__ qkv,
                bf16_t* __restrict__ vg, bf16_t* __restrict__ qg,
                bf16_t* __restrict__ kg) {
  G8_DECL
  const int n = blockIdx.x;
  long row0, col0;
  int aoff2;
  const bf16_t* pAt;
  if (n < 256) {
    const int xcd = n & 7, j = n >> 3;
    const int ct = j >> 3;
    row0 = (long)(xcd * 8 + (j & 7)) * 256;             // [0,16384)
    col0 = ct * 256 + (ct >= 2 ? 512 : 0);
    aoff2 = 131072;
    pAt = A + (row0 + t7) * 1024 + t8 * 8;
  } else {
    const int m2 = n - 256;
    const int xcd = m2 & 7, j = m2 >> 3;
    const int ct = j >> 2;
    row0 = (long)(xcd * 4 + (j & 3)) * 256;             // [0,8192)
    col0 = (ct < 2) ? (512 + ct * 256) : (1536 + (ct - 2) * 256);
    aoff2 = 262144;
    long r = row0 + t7;
    if (r > 8063) r = 8063;                              // defensive clamp
    const long g = ((r >> 5) << 6) + 32 + (r & 31);      // gathered global row
    pAt = A + g * 1024 + t8 * 8;
  }
  const bf16_t* pBt = Wcat + (col0 + t7) * 1024 + t8 * 8;
  G8_MAIN
  bf16_t* dst; long ld, cofs;
  if (col0 < 512)       { dst = qkv; ld = 1024; cofs = 0; }
  else if (col0 < 1024) { dst = vg;  ld = 512;  cofs = 512; }
  else if (col0 < 1536) { dst = qg;  ld = 512;  cofs = 1024; }
  else                  { dst = kg;  ld = 512;  cofs = 1536; }
#pragma unroll
  for (int nt = 0; nt < 4; ++nt) {
    const long col = col0 + wc + nt * 16 + lm;
    const float bc = bcat[col];
    const long cl = col - cofs;
#pragma unroll
    for (int mt = 0; mt < 8; ++mt) {
#pragma unroll
      for (int r = 0; r < 4; ++r) {
        const long row = row0 + wr + mt * 16 + lq * 4 + r;
        dst[row * ld + cl] = (bf16_t)(acc[mt][nt][r] + bc);
      }
    }
  }
}

// out-projection GEMM: M=16384, N=1024 -> 256 blocks, ROW-BAND swizzle:
// xcd owns rows (xcd*8+(j&7))*256 x 4 col tiles (A-band 4MB + Wob 2MB in L2).
__global__ __launch_bounds__(512, 2)
void gemm_bt(const bf16_t* __restrict__ A, const bf16_t* __restrict__ W,
             const float* __restrict__ bias, float* __restrict__ C, int ldc) {
  G8_DECL
  const int n = blockIdx.x, xcd = n & 7, j = n >> 3;  // j in [0,32)
  const long row0 = (long)(xcd * 8 + (j & 7)) * 256;  // [0,16384)
  const long col0 = (long)(j >> 3) * 256;             // [0,1024)
  const int aoff2 = 131072;
  const bf16_t* pAt = A + (row0 + t7) * 1024 + t8 * 8;
  const bf16_t* pBt = W + (col0 + t7) * 1024 + t8 * 8;
  G8_MAIN
#pragma unroll
  for (int nt = 0; nt < 4; ++nt) {
    const long col = col0 + wc + nt * 16 + lm;
    const float bc = bias[col];
#pragma unroll
    for (int mt = 0; mt < 8; ++mt) {
#pragma unroll
      for (int r = 0; r < 4; ++r) {
        const long row = row0 + wr + mt * 16 + lq * 4 + r;
        C[row * (long)ldc + col] = acc[mt][nt][r] + bc;
      }
    }
  }
}

// ---------------------------------------------------------------------------
// Sparse attention for global heads. Block = (qt, h, b): 64 query rows,
// 256 selected keys: token(l) = 64*(l>>2) + 32 + 4*h + (l&3).
// kg/vg are PACKED: packed row = 32*(token>>6) + (token&63) - 32
//                              = ((l>>2)<<5) + 4*h + (l&3), 2048 rows/batch.
// ---------------------------------------------------------------------------
__global__ __launch_bounds__(256, 1)
void attn_sparse(const bf16_t* __restrict__ qg, const bf16_t* __restrict__ kg,
                 const bf16_t* __restrict__ vg, const int* __restrict__ mask,
                 bf16_t* __restrict__ qkv) {
  __shared__ bf16_t Ks[16384];        // frag-order: chunk = kq*256 + lkey
  __shared__ bf16_t Vt[64 * 264];     // Vt[d][lkey], row stride 264 (+8 pad)
  __shared__ bf16_t Ps[4 * 16 * 136]; // per-wave P half-tile, stride 136 (+8 pad)
  __shared__ int smask[256];

  const int tid = threadIdx.x;
  const int b = blockIdx.z, h = blockIdx.y, qt = blockIdx.x;

  {
    const int lk = tid;
    const int token = ((lk >> 2) << 6) + 32 + (h << 2) + (lk & 3);
    const int selrow = ((lk >> 2) << 5) + (h << 2) + (lk & 3);
    const size_t rowi = (size_t)(b * 2048 + selrow);
    const uint4* ksrc = (const uint4*)(kg + rowi * 512 + h * 64);
#pragma unroll
    for (int kq = 0; kq < 8; ++kq)
      *(uint4*)(Ks + (kq * 256 + lk) * 8) = ksrc[kq];
    const bf16_t* vsrc = vg + rowi * 512 + h * 64;
#pragma unroll
    for (int i = 0; i < 8; ++i) {
      bf16x8 vv = *(const bf16x8*)(vsrc + i * 8);
#pragma unroll
      for (int j = 0; j < 8; ++j) Vt[(i * 8 + j) * 264 + lk] = vv[j];
    }
    smask[lk] = mask[b * 4096 + token];
  }
  __syncthreads();

  const int w = tid >> 6, l = tid & 63, lq = l >> 4, lm = l & 15;
  const int mrow = (qt << 6) + (w << 4);

  const bf16_t* qrow = qg + (size_t)(b * 4096 + mrow + lm) * 512 + h * 64 + lq * 8;
  bf16x8 aq0 = *(const bf16x8*)qrow;
  bf16x8 aq1 = *(const bf16x8*)(qrow + 32);

  floatx4 zero4 = {0.f, 0.f, 0.f, 0.f};
  floatx4 s[16];
#pragma unroll
  for (int t = 0; t < 16; ++t) {
    bf16x8 kb0 = *(const bf16x8*)(Ks + (lq * 256 + t * 16 + lm) * 8);
    bf16x8 kb1 = *(const bf16x8*)(Ks + ((4 + lq) * 256 + t * 16 + lm) * 8);
    floatx4 z = zero4;
    z = MFMA16(aq0, kb0, z);
    z = MFMA16(aq1, kb1, z);
    s[t] = z;
  }

  float rmax[4] = {-1e30f, -1e30f, -1e30f, -1e30f};
#pragma unroll
  for (int t = 0; t < 16; ++t) {
    const bool mk = smask[t * 16 + lm] != 0;
#pragma unroll
    for (int r = 0; r < 4; ++r) {
      float v = s[t][r] * 0.125f;
      v = mk ? -1e10f : v;
      s[t][r] = v;
      rmax[r] = fmaxf(rmax[r], v);
    }
  }
#pragma unroll
  for (int off = 1; off < 16; off <<= 1)
#pragma unroll
    for (int r = 0; r < 4; ++r) rmax[r] = fmaxf(rmax[r], __shfl_xor(rmax[r], off));
  float rsum[4] = {0.f, 0.f, 0.f, 0.f};
#pragma unroll
  for (int t = 0; t < 16; ++t)
#pragma unroll
    for (int r = 0; r < 4; ++r) {
      float p = __expf(s[t][r] - rmax[r]);
      s[t][r] = p;
      rsum[r] += p;
    }
#pragma unroll
  for (int off = 1; off < 16; off <<= 1)
#pragma unroll
    for (int r = 0; r < 4; ++r) rsum[r] += __shfl_xor(rsum[r], off);
  float rinv[4];
#pragma unroll
  for (int r = 0; r < 4; ++r) rinv[r] = 1.0f / rsum[r];

  floatx4 o[4];
#pragma unroll
  for (int dt = 0; dt < 4; ++dt) o[dt] = zero4;
  bf16_t* Pw = Ps + w * (16 * 136);
#pragma unroll
  for (int half = 0; half < 2; ++half) {
#pragma unroll
    for (int t = 0; t < 8; ++t) {
      const int tt = half * 8 + t;
#pragma unroll
      for (int r = 0; r < 4; ++r)
        Pw[(lq * 4 + r) * 136 + t * 16 + lm] = (bf16_t)(s[tt][r] * rinv[r]);
    }
    __syncthreads();
#pragma unroll
    for (int ks = 0; ks < 4; ++ks) {
      bf16x8 pa = *(const bf16x8*)(Pw + lm * 136 + ks * 32 + lq * 8);
#pragma unroll
      for (int dt = 0; dt < 4; ++dt) {
        bf16x8 vb = *(const bf16x8*)(Vt + (dt * 16 + lm) * 264 + half * 128 + ks * 32 + lq * 8);
        o[dt] = MFMA16(pa, vb, o[dt]);
      }
    }
    __syncthreads();
  }

#pragma unroll
  for (int dt = 0; dt < 4; ++dt) {
    const int d = dt * 16 + lm;
#pragma unroll
    for (int r = 0; r < 4; ++r) {
      const int token = mrow + lq * 4 + r;
      qkv[(size_t)(b * 4096 + token) * 1024 + 512 + h * 64 + d] = (bf16_t)o[dt][r];
    }
  }
}

// ---------------------------------------------------------------------------
extern "C" void kernel_launch(void* const* d_in, const int* in_sizes, int n_in,
                              void* d_out, int out_size, void* d_ws, size_t ws_size,
                              hipStream_t stream) {
  const float* x   = (const float*)d_in[0];
  const int* mask  = (const int*)d_in[1];
  const float* Wq  = (const float*)d_in[2];
  const float* bq  = (const float*)d_in[3];
  const float* Wk  = (const float*)d_in[4];
  const float* bk  = (const float*)d_in[5];
  const float* Wv  = (const float*)d_in[6];
  const float* bv  = (const float*)d_in[7];
  const float* Wo  = (const float*)d_in[8];
  const float* bo  = (const float*)d_in[9];
  float* out = (float*)d_out;

  // ws: xb 32MB | Wcat 4MB | Wob 2MB | bcat 8KB | vg | qg | kg | qkv
  char* ws = (char*)d_ws;
  bf16_t* xb   = (bf16_t*)(ws);
  bf16_t* Wcat = (bf16_t*)(ws + 33554432L);
  bf16_t* Wob  = (bf16_t*)(ws + 37748736L);
  float*  bcat = (float*)(ws + 39845888L);
  bf16_t* vg   = (bf16_t*)(ws + 39854080L);   // packed 4x2048x512 bf16 = 8MB
  bf16_t* qg   = (bf16_t*)(ws + 56631296L);   // full 16384x512 bf16 = 16MB
  bf16_t* kg   = (bf16_t*)(ws + 73408512L);   // packed 4x2048x512 bf16 = 8MB
  bf16_t* qkv  = (bf16_t*)(ws + 90185728L);   // 16384x1024 bf16 = 32MB

  dim3 blk(256);
  cvt_f32_bf16<<<16384, blk, 0, stream>>>(x, xb, 16777216);
  cvt_f32_bf16<<<1024, blk, 0, stream>>>(Wv, Wcat, 1048576);
  cvt_f32_bf16<<<512, blk, 0, stream>>>(Wq + 524288, Wcat + 1048576, 524288);
  cvt_f32_bf16<<<512, blk, 0, stream>>>(Wk + 524288, Wcat + 1572864, 524288);
  cvt_f32_bf16<<<1024, blk, 0, stream>>>(Wo, Wob, 1048576);
  pack_bias<<<8, blk, 0, stream>>>(bv, bq, bk, bcat);

  gemm_fused<<<384, dim3(512), 0, stream>>>(xb, Wcat, bcat, qkv, vg, qg, kg);
  attn_sparse<<<dim3(64, 8, 4), dim3(256), 0, stream>>>(qg, kg, vg, mask, qkv);
  gemm_bt<<<256, dim3(512), 0, stream>>>(qkv, Wob, bo, out, 1024);
}

// Round 7
// 320.806 us; speedup vs baseline: 1.2832x; 1.0885x over previous
//
#include <hip/hip_runtime.h>
#include <stdint.h>

// ---------------------------------------------------------------------------
// Sparse attention, MI355X. f32 I/O, bf16 MFMA internals.
//   0) xb = bf16(x); Wcat = bf16([Wv; Wq[512:]; Wk[512:]]); Wob = bf16(Wo)
//   1) gemm_fused (384 blocks, one dispatch):
//        proj1 (256 blk): all 16384 rows x [Wv-local(512) | Wq-glob(512)]
//                         -> qkv[:, :512], qg
//        proj2 (128 blk): 8192 SELECTED rows (tokens 32..63 mod 64, packed)
//                         x [Wv-glob(512) | Wk-glob(512)] -> vg, kg (packed)
//   2) qkv[:, 512:] = sparse_attention(qg, kg, vg, mask)  (kg/vg packed rows)
//   3) out(f32) = qkv @ Wob^T + bo
//
// GEMM core: r3-verified 8-phase schedule (256x256, BK=64, 8 waves, 2 LDS
// buffers, counted vmcnt ph2/ph6/ph8, raw barriers + lgkmcnt fences).
// XCD swizzle: ROW-BAND ownership (r6-proven: FETCH 41MB).
//
// attn this round: ONE block per (b,h,q-octile): grid (8,8,4)=256 blocks
// (1/CU, single round), 512 thr = 8 waves. K/V/mask staged ONCE per block
// (8x less gather traffic vs per-q-tile blocks); each wave free-runs 4
// independent 16-row q-passes with NO cross-wave barriers after the stage
// (Ps is wave-private, Ks/Vt read-only). MFMA/softmax/layouts identical to
// the r6-verified code.
// ---------------------------------------------------------------------------

typedef __bf16 bf16_t;
typedef __bf16 bf16x4 __attribute__((ext_vector_type(4)));
typedef __bf16 bf16x8 __attribute__((ext_vector_type(8)));
typedef float floatx4 __attribute__((ext_vector_type(4)));

#define MFMA16(a, b, c) __builtin_amdgcn_mfma_f32_16x16x32_bf16((a), (b), (c), 0, 0, 0)

// async global->LDS, 16B per lane; LDS dest = wave-uniform base + lane*16
__device__ __forceinline__ void glds16(const bf16_t* g, const bf16_t* lds_base) {
  __builtin_amdgcn_global_load_lds(
      (const __attribute__((address_space(1))) uint32_t*)(uintptr_t)g,
      (__attribute__((address_space(3))) uint32_t*)(uintptr_t)lds_base, 16, 0, 0);
}

#define VMCNT(n)  asm volatile("s_waitcnt vmcnt(" #n ")" ::: "memory")
#define LGKMCNT0  asm volatile("s_waitcnt lgkmcnt(0)" ::: "memory")
#define SBAR      __builtin_amdgcn_s_barrier()
#define SCHED0    __builtin_amdgcn_sched_barrier(0)

// ---------------------------------------------------------------------------
__global__ void cvt_f32_bf16(const float* __restrict__ src, bf16_t* __restrict__ dst, int n) {
  const int i = (blockIdx.x * 256 + threadIdx.x) * 4;
  if (i < n) {
    float4 v = *(const float4*)(src + i);
    bf16x4 d = {(bf16_t)v.x, (bf16_t)v.y, (bf16_t)v.z, (bf16_t)v.w};
    *(bf16x4*)(dst + i) = d;
  }
}

// bcat = [bv(1024); bq[512:](512); bk[512:](512)]  (f32, 2048)
__global__ void pack_bias(const float* __restrict__ bv, const float* __restrict__ bq,
                          const float* __restrict__ bk, float* __restrict__ bcat) {
  const int i = blockIdx.x * 256 + threadIdx.x;  // 2048 threads
  float v;
  if (i < 1024) v = bv[i];
  else if (i < 1536) v = bq[i - 512];
  else v = bk[i - 1024];
  bcat[i] = v;
}

// ---------------------------------------------------------------------------
// 8-phase 256x256 GEMM core (r3-verified). LDS chunk layout per buffer:
//   chunk c = oct*256 + idx  holds Mat[base+idx][tile*64 + oct*8 .. +8]
// ---------------------------------------------------------------------------
#define G8_DECL                                                                 \
  __shared__ bf16_t As[2][16384];                                               \
  __shared__ bf16_t Bs[2][16384];                                               \
  const int tid = threadIdx.x;                                                  \
  const int w = tid >> 6, l = tid & 63;                                         \
  const int lq = l >> 4, lm = l & 15;                                           \
  const int wr = (w >> 2) << 7;   /* wave row offset 0/128 */                   \
  const int wc = (w & 3) << 6;    /* wave col offset 0/64/128/192 */            \
  floatx4 acc[8][4];                                                            \
  { floatx4 z = {0.f, 0.f, 0.f, 0.f};                                           \
    _Pragma("unroll") for (int i = 0; i < 8; ++i)                               \
    _Pragma("unroll") for (int j = 0; j < 4; ++j) acc[i][j] = z; }              \
  const int t7 = tid & 127, t8 = tid >> 7;                                      \
  const int sbase = ((((w >> 1) << 8) + ((w & 1) << 6)) << 3);

#define G8_ST_A(s, off, jk)                                                     \
  glds16(pAt + (off),         &As[s][0] + ((jk) << 13) + sbase);                \
  glds16(pAt + aoff2 + (off), &As[s][0] + ((jk) << 13) + 1024 + sbase);
#define G8_ST_B(s, off, jk)                                                     \
  glds16(pBt + (off),          &Bs[s][0] + ((jk) << 13) + sbase);               \
  glds16(pBt + 131072 + (off), &Bs[s][0] + ((jk) << 13) + 1024 + sbase);

#define G8_READ_B(s, kk)                                                        \
  _Pragma("unroll") for (int nt = 0; nt < 4; ++nt)                              \
    bfr[nt] = *(const bf16x8*)(&Bs[s][0] +                                      \
        (((((kk) * 4 + lq) << 8) + wc + nt * 16 + lm) << 3));

#define G8_READ_A(s, kk, mh)                                                    \
  _Pragma("unroll") for (int i = 0; i < 4; ++i)                                 \
    af[i] = *(const bf16x8*)(&As[s][0] +                                        \
        (((((kk) * 4 + lq) << 8) + wr + (mh) * 64 + i * 16 + lm) << 3));

#define G8_MFMA(mh)                                                             \
  __builtin_amdgcn_s_setprio(1);                                                \
  _Pragma("unroll") for (int i = 0; i < 4; ++i)                                 \
    _Pragma("unroll") for (int nt = 0; nt < 4; ++nt)                            \
      acc[(mh) * 4 + i][nt] = MFMA16(af[i], bfr[nt], acc[(mh) * 4 + i][nt]);    \
  __builtin_amdgcn_s_setprio(0);

#define PH_PRE   SCHED0; SBAR; LGKMCNT0; SCHED0;
#define PH_POST  SCHED0; SBAR; SCHED0;

// Stage/retire ledger identical to r3 (verified): vmcnt(4)@ph2 retires prev
// ph5-8; vmcnt(8)@ph6 retires ph1-2; vmcnt(8)@ph8 retires ph3-4. Never 0 in
// the main loop; tail peeled with vmcnt(4)/vmcnt(0).
#define G8_ITER                                                                 \
    G8_READ_A(0, 0, 0) G8_READ_B(0, 0)                                          \
    G8_ST_A(1, 96, 1)                                                           \
    PH_PRE G8_MFMA(0) PH_POST                                                   \
    G8_READ_A(0, 0, 1)                                                          \
    G8_ST_B(1, 96, 1)                                                           \
    VMCNT(4);                                                                   \
    PH_PRE G8_MFMA(1) PH_POST                                                   \
    G8_READ_A(0, 1, 0) G8_READ_B(0, 1)                                          \
    G8_ST_A(0, 128, 0)                                                          \
    PH_PRE G8_MFMA(0) PH_POST                                                   \
    G8_READ_A(0, 1, 1)                                                          \
    G8_ST_B(0, 128, 0)                                                          \
    PH_PRE G8_MFMA(1) PH_POST                                                   \
    G8_READ_A(1, 0, 0) G8_READ_B(1, 0)                                          \
    G8_ST_A(0, 160, 1)                                                          \
    PH_PRE G8_MFMA(0) PH_POST                                                   \
    G8_READ_A(1, 0, 1)                                                          \
    G8_ST_B(0, 160, 1)                                                          \
    VMCNT(8);                                                                   \
    PH_PRE G8_MFMA(1) PH_POST                                                   \
    G8_READ_A(1, 1, 0) G8_READ_B(1, 1)                                          \
    G8_ST_A(1, 192, 0)                                                          \
    PH_PRE G8_MFMA(0) PH_POST                                                   \
    G8_READ_A(1, 1, 1)                                                          \
    G8_ST_B(1, 192, 0)                                                          \
    VMCNT(8);                                                                   \
    PH_PRE G8_MFMA(1) PH_POST

#define G8_TAIL                                                                 \
    G8_READ_A(0, 0, 0) G8_READ_B(0, 0)                                          \
    G8_ST_A(1, 96, 1)                                                           \
    PH_PRE G8_MFMA(0) PH_POST                                                   \
    G8_READ_A(0, 0, 1)                                                          \
    G8_ST_B(1, 96, 1)                                                           \
    VMCNT(4);                                                                   \
    PH_PRE G8_MFMA(1) PH_POST                                                   \
    G8_READ_A(0, 1, 0) G8_READ_B(0, 1)                                          \
    PH_PRE G8_MFMA(0) PH_POST                                                   \
    G8_READ_A(0, 1, 1)                                                          \
    PH_PRE G8_MFMA(1) PH_POST                                                   \
    G8_READ_A(1, 0, 0) G8_READ_B(1, 0)                                          \
    PH_PRE G8_MFMA(0) PH_POST                                                   \
    G8_READ_A(1, 0, 1)                                                          \
    VMCNT(0);                                                                   \
    PH_PRE G8_MFMA(1) PH_POST                                                   \
    G8_READ_A(1, 1, 0) G8_READ_B(1, 1)                                          \
    PH_PRE G8_MFMA(0) PH_POST                                                   \
    G8_READ_A(1, 1, 1)                                                          \
    PH_PRE G8_MFMA(1) PH_POST

#define G8_MAIN                                                                 \
  G8_ST_A(0, 0, 0) G8_ST_B(0, 0, 0)                                             \
  G8_ST_A(0, 32, 1) G8_ST_B(0, 32, 1)                                           \
  G8_ST_A(1, 64, 0) G8_ST_B(1, 64, 0)                                           \
  VMCNT(0); SBAR; SCHED0;                                                       \
  bf16x8 af[4], bfr[4];                                                         \
  for (int t = 0; t < 7; ++t) {                                                 \
    G8_ITER                                                                     \
    pAt += 128; pBt += 128;                                                     \
  }                                                                             \
  G8_TAIL

// ---------------------------------------------------------------------------
// Fused projection: 384 blocks, ROW-BAND XCD swizzle (r6-verified).
// ---------------------------------------------------------------------------
__global__ __launch_bounds__(512, 2)
void gemm_fused(const bf16_t* __restrict__ A, const bf16_t* __restrict__ Wcat,
                const float* __restrict__ bcat, bf16_t* __restrict__ qkv,
                bf16_t* __restrict__ vg, bf16_t* __restrict__ qg,
                bf16_t* __restrict__ kg) {
  G8_DECL
  const int n = blockIdx.x;
  long row0, col0;
  int aoff2;
  const bf16_t* pAt;
  if (n < 256) {
    const int xcd = n & 7, j = n >> 3;
    const int ct = j >> 3;
    row0 = (long)(xcd * 8 + (j & 7)) * 256;             // [0,16384)
    col0 = ct * 256 + (ct >= 2 ? 512 : 0);
    aoff2 = 131072;
    pAt = A + (row0 + t7) * 1024 + t8 * 8;
  } else {
    const int m2 = n - 256;
    const int xcd = m2 & 7, j = m2 >> 3;
    const int ct = j >> 2;
    row0 = (long)(xcd * 4 + (j & 3)) * 256;             // [0,8192)
    col0 = (ct < 2) ? (512 + ct * 256) : (1536 + (ct - 2) * 256);
    aoff2 = 262144;
    long r = row0 + t7;
    if (r > 8063) r = 8063;                              // defensive clamp
    const long g = ((r >> 5) << 6) + 32 + (r & 31);      // gathered global row
    pAt = A + g * 1024 + t8 * 8;
  }
  const bf16_t* pBt = Wcat + (col0 + t7) * 1024 + t8 * 8;
  G8_MAIN
  bf16_t* dst; long ld, cofs;
  if (col0 < 512)       { dst = qkv; ld = 1024; cofs = 0; }
  else if (col0 < 1024) { dst = vg;  ld = 512;  cofs = 512; }
  else if (col0 < 1536) { dst = qg;  ld = 512;  cofs = 1024; }
  else                  { dst = kg;  ld = 512;  cofs = 1536; }
#pragma unroll
  for (int nt = 0; nt < 4; ++nt) {
    const long col = col0 + wc + nt * 16 + lm;
    const float bc = bcat[col];
    const long cl = col - cofs;
#pragma unroll
    for (int mt = 0; mt < 8; ++mt) {
#pragma unroll
      for (int r = 0; r < 4; ++r) {
        const long row = row0 + wr + mt * 16 + lq * 4 + r;
        dst[row * ld + cl] = (bf16_t)(acc[mt][nt][r] + bc);
      }
    }
  }
}

// out-projection GEMM: M=16384, N=1024 -> 256 blocks, ROW-BAND swizzle.
__global__ __launch_bounds__(512, 2)
void gemm_bt(const bf16_t* __restrict__ A, const bf16_t* __restrict__ W,
             const float* __restrict__ bias, float* __restrict__ C, int ldc) {
  G8_DECL
  const int n = blockIdx.x, xcd = n & 7, j = n >> 3;  // j in [0,32)
  const long row0 = (long)(xcd * 8 + (j & 7)) * 256;  // [0,16384)
  const long col0 = (long)(j >> 3) * 256;             // [0,1024)
  const int aoff2 = 131072;
  const bf16_t* pAt = A + (row0 + t7) * 1024 + t8 * 8;
  const bf16_t* pBt = W + (col0 + t7) * 1024 + t8 * 8;
  G8_MAIN
#pragma unroll
  for (int nt = 0; nt < 4; ++nt) {
    const long col = col0 + wc + nt * 16 + lm;
    const float bc = bias[col];
#pragma unroll
    for (int mt = 0; mt < 8; ++mt) {
#pragma unroll
      for (int r = 0; r < 4; ++r) {
        const long row = row0 + wr + mt * 16 + lq * 4 + r;
        C[row * (long)ldc + col] = acc[mt][nt][r] + bc;
      }
    }
  }
}

// ---------------------------------------------------------------------------
// Sparse attention for global heads. Block = (qq, h, b): 512 query rows
// (q-octile), 256 selected keys: token(lk) = 64*(lk>>2) + 32 + 4*h + (lk&3).
// kg/vg PACKED: packed row = ((lk>>2)<<5) + 4*h + (lk&3), 2048 rows/batch.
// 512 threads = 8 waves; K/V/mask staged once; each wave runs 4 independent
// 16-row q-passes with no cross-wave barriers (Ps is wave-private).
// ---------------------------------------------------------------------------
__global__ __launch_bounds__(512, 1)
void attn_sparse(const bf16_t* __restrict__ qg, const bf16_t* __restrict__ kg,
                 const bf16_t* __restrict__ vg, const int* __restrict__ mask,
                 bf16_t* __restrict__ qkv) {
  __shared__ bf16_t Ks[16384];        // frag-order: chunk = kq*256 + lkey (32KB)
  __shared__ bf16_t Vt[64 * 264];     // Vt[d][lkey], stride 264 (+8 pad) (33KB)
  __shared__ bf16_t Ps[8 * 16 * 136]; // per-wave P half-tile, stride 136 (34KB)
  __shared__ int smask[256];

  const int tid = threadIdx.x;
  const int b = blockIdx.z, h = blockIdx.y, qq = blockIdx.x;  // qq in [0,8)

  {
    const int lk = tid & 255;
    const int hf = tid >> 8;  // 0/1: split the 8 chunks between thread halves
    const int selrow = ((lk >> 2) << 5) + (h << 2) + (lk & 3);
    const size_t rowi = (size_t)(b * 2048 + selrow);
    const uint4* ksrc = (const uint4*)(kg + rowi * 512 + h * 64);
#pragma unroll
    for (int kq = 0; kq < 4; ++kq) {
      const int kq8 = hf * 4 + kq;
      *(uint4*)(Ks + (kq8 * 256 + lk) * 8) = ksrc[kq8];
    }
    const bf16_t* vsrc = vg + rowi * 512 + h * 64;
#pragma unroll
    for (int i = 0; i < 4; ++i) {
      const int i8 = hf * 4 + i;
      bf16x8 vv = *(const bf16x8*)(vsrc + i8 * 8);
#pragma unroll
      for (int j = 0; j < 8; ++j) Vt[(i8 * 8 + j) * 264 + lk] = vv[j];
    }
    if (tid < 256) {
      const int token = ((lk >> 2) << 6) + 32 + (h << 2) + (lk & 3);
      smask[lk] = mask[b * 4096 + token];
    }
  }
  __syncthreads();

  const int w = tid >> 6, l = tid & 63, lq = l >> 4, lm = l & 15;
  bf16_t* Pw = Ps + w * (16 * 136);
  floatx4 zero4 = {0.f, 0.f, 0.f, 0.f};

  for (int p = 0; p < 4; ++p) {
    const int mrow = (qq << 9) + ((p * 8 + w) << 4);  // 16-row q-tile base

    const bf16_t* qrow = qg + (size_t)(b * 4096 + mrow + lm) * 512 + h * 64 + lq * 8;
    bf16x8 aq0 = *(const bf16x8*)qrow;
    bf16x8 aq1 = *(const bf16x8*)(qrow + 32);

    floatx4 s[16];
#pragma unroll
    for (int t = 0; t < 16; ++t) {
      bf16x8 kb0 = *(const bf16x8*)(Ks + (lq * 256 + t * 16 + lm) * 8);
      bf16x8 kb1 = *(const bf16x8*)(Ks + ((4 + lq) * 256 + t * 16 + lm) * 8);
      floatx4 z = zero4;
      z = MFMA16(aq0, kb0, z);
      z = MFMA16(aq1, kb1, z);
      s[t] = z;
    }

    float rmax[4] = {-1e30f, -1e30f, -1e30f, -1e30f};
#pragma unroll
    for (int t = 0; t < 16; ++t) {
      const bool mk = smask[t * 16 + lm] != 0;
#pragma unroll
      for (int r = 0; r < 4; ++r) {
        float v = s[t][r] * 0.125f;
        v = mk ? -1e10f : v;
        s[t][r] = v;
        rmax[r] = fmaxf(rmax[r], v);
      }
    }
#pragma unroll
    for (int off = 1; off < 16; off <<= 1)
#pragma unroll
      for (int r = 0; r < 4; ++r) rmax[r] = fmaxf(rmax[r], __shfl_xor(rmax[r], off));
    float rsum[4] = {0.f, 0.f, 0.f, 0.f};
#pragma unroll
    for (int t = 0; t < 16; ++t)
#pragma unroll
      for (int r = 0; r < 4; ++r) {
        float pp = __expf(s[t][r] - rmax[r]);
        s[t][r] = pp;
        rsum[r] += pp;
      }
#pragma unroll
    for (int off = 1; off < 16; off <<= 1)
#pragma unroll
      for (int r = 0; r < 4; ++r) rsum[r] += __shfl_xor(rsum[r], off);
    float rinv[4];
#pragma unroll
    for (int r = 0; r < 4; ++r) rinv[r] = 1.0f / rsum[r];

    floatx4 o[4];
#pragma unroll
    for (int dt = 0; dt < 4; ++dt) o[dt] = zero4;
#pragma unroll
    for (int half = 0; half < 2; ++half) {
#pragma unroll
      for (int t = 0; t < 8; ++t) {
        const int tt = half * 8 + t;
#pragma unroll
        for (int r = 0; r < 4; ++r)
          Pw[(lq * 4 + r) * 136 + t * 16 + lm] = (bf16_t)(s[tt][r] * rinv[r]);
      }
      // Pw is wave-private: ds_write -> ds_read ordering is handled by the
      // compiler's lgkmcnt tracking; no block barrier needed.
#pragma unroll
      for (int ks = 0; ks < 4; ++ks) {
        bf16x8 pa = *(const bf16x8*)(Pw + lm * 136 + ks * 32 + lq * 8);
#pragma unroll
        for (int dt = 0; dt < 4; ++dt) {
          bf16x8 vb = *(const bf16x8*)(Vt + (dt * 16 + lm) * 264 + half * 128 + ks * 32 + lq * 8);
          o[dt] = MFMA16(pa, vb, o[dt]);
        }
      }
    }

#pragma unroll
    for (int dt = 0; dt < 4; ++dt) {
      const int d = dt * 16 + lm;
#pragma unroll
      for (int r = 0; r < 4; ++r) {
        const int token = mrow + lq * 4 + r;
        qkv[(size_t)(b * 4096 + token) * 1024 + 512 + h * 64 + d] = (bf16_t)o[dt][r];
      }
    }
  }
}

// ---------------------------------------------------------------------------
extern "C" void kernel_launch(void* const* d_in, const int* in_sizes, int n_in,
                              void* d_out, int out_size, void* d_ws, size_t ws_size,
                              hipStream_t stream) {
  const float* x   = (const float*)d_in[0];
  const int* mask  = (const int*)d_in[1];
  const float* Wq  = (const float*)d_in[2];
  const float* bq  = (const float*)d_in[3];
  const float* Wk  = (const float*)d_in[4];
  const float* bk  = (const float*)d_in[5];
  const float* Wv  = (const float*)d_in[6];
  const float* bv  = (const float*)d_in[7];
  const float* Wo  = (const float*)d_in[8];
  const float* bo  = (const float*)d_in[9];
  float* out = (float*)d_out;

  // ws: xb 32MB | Wcat 4MB | Wob 2MB | bcat 8KB | vg | qg | kg | qkv
  char* ws = (char*)d_ws;
  bf16_t* xb   = (bf16_t*)(ws);
  bf16_t* Wcat = (bf16_t*)(ws + 33554432L);
  bf16_t* Wob  = (bf16_t*)(ws + 37748736L);
  float*  bcat = (float*)(ws + 39845888L);
  bf16_t* vg   = (bf16_t*)(ws + 39854080L);   // packed 4x2048x512 bf16 = 8MB
  bf16_t* qg   = (bf16_t*)(ws + 56631296L);   // full 16384x512 bf16 = 16MB
  bf16_t* kg   = (bf16_t*)(ws + 73408512L);   // packed 4x2048x512 bf16 = 8MB
  bf16_t* qkv  = (bf16_t*)(ws + 90185728L);   // 16384x1024 bf16 = 32MB

  dim3 blk(256);
  cvt_f32_bf16<<<16384, blk, 0, stream>>>(x, xb, 16777216);
  cvt_f32_bf16<<<1024, blk, 0, stream>>>(Wv, Wcat, 1048576);
  cvt_f32_bf16<<<512, blk, 0, stream>>>(Wq + 524288, Wcat + 1048576, 524288);
  cvt_f32_bf16<<<512, blk, 0, stream>>>(Wk + 524288, Wcat + 1572864, 524288);
  cvt_f32_bf16<<<1024, blk, 0, stream>>>(Wo, Wob, 1048576);
  pack_bias<<<8, blk, 0, stream>>>(bv, bq, bk, bcat);

  gemm_fused<<<384, dim3(512), 0, stream>>>(xb, Wcat, bcat, qkv, vg, qg, kg);
  attn_sparse<<<dim3(8, 8, 4), dim3(512), 0, stream>>>(qg, kg, vg, mask, qkv);
  gemm_bt<<<256, dim3(512), 0, stream>>>(qkv, Wob, bo, out, 1024);
}

// Round 8
// 303.728 us; speedup vs baseline: 1.3554x; 1.0562x over previous
//
#include <hip/hip_runtime.h>
#include <stdint.h>

// ---------------------------------------------------------------------------
// Sparse attention, MI355X. f32 I/O, bf16 MFMA internals.
//   0) prep (one dispatch): xb=bf16(x); Wcat=bf16([Wv;Wq[512:];Wk[512:]]);
//      Wob=bf16(Wo); bcat=[bv;bq[512:];bk[512:]]
//   1) gemm_fused (256 blocks, perfectly balanced: each block = 1 proj1 tile
//      + 1 proj2 half-tile = 1.5 tile-units, one round, zero idle CUs):
//        phase 1: all 16384 rows x [Wv-local | Wq-glob] -> qkv[:, :512], qg
//        phase 2: 8192 SELECTED rows (tokens 32..63 mod 64, packed) x
//                 [Wv-glob | Wk-glob] 256x128 half-tiles -> vg, kg (packed)
//      Phase-2 A rows are a subset of the block's phase-1 XCD A-band -> L2 hits.
//   2) qkv[:, 512:] = sparse_attention(qg, kg, vg, mask)  (r7-verified)
//   3) out(f32) = qkv @ Wob^T + bo
//
// GEMM core: r3-verified 8-phase schedule (256-wide tiles, BK=64, 8 waves,
// 2 LDS buffers, counted vmcnt, raw barriers + lgkmcnt fences).
// Phase-2 ledger ({A:2,B:1} loads/phase): VMCNT(3)@ph2 keeps ph1-2 (retires
// prev ph5-8); VMCNT(6)@ph6 keeps ph3-6 (retires ph1-2 before ph7 reads
// buf1.k1); VMCNT(6)@ph8 keeps ph5-8 (retires ph3-4 before next ph1).
// XCD swizzle: ROW-BAND ownership (r6-proven: FETCH 41MB).
// ---------------------------------------------------------------------------

typedef __bf16 bf16_t;
typedef __bf16 bf16x4 __attribute__((ext_vector_type(4)));
typedef __bf16 bf16x8 __attribute__((ext_vector_type(8)));
typedef float floatx4 __attribute__((ext_vector_type(4)));

#define MFMA16(a, b, c) __builtin_amdgcn_mfma_f32_16x16x32_bf16((a), (b), (c), 0, 0, 0)

// async global->LDS, 16B per lane; LDS dest = wave-uniform base + lane*16
__device__ __forceinline__ void glds16(const bf16_t* g, const bf16_t* lds_base) {
  __builtin_amdgcn_global_load_lds(
      (const __attribute__((address_space(1))) uint32_t*)(uintptr_t)g,
      (__attribute__((address_space(3))) uint32_t*)(uintptr_t)lds_base, 16, 0, 0);
}

#define VMCNT(n)  asm volatile("s_waitcnt vmcnt(" #n ")" ::: "memory")
#define LGKMCNT0  asm volatile("s_waitcnt lgkmcnt(0)" ::: "memory")
#define SBAR      __builtin_amdgcn_s_barrier()
#define SCHED0    __builtin_amdgcn_sched_barrier(0)

// ---------------------------------------------------------------------------
// prep: all f32->bf16 conversions + bias pack in ONE dispatch (saves 5 graph
// node gaps). Exact block ranges; all segment sizes are multiples of 1024 f32.
// ---------------------------------------------------------------------------
__global__ void prep(const float* __restrict__ x, const float* __restrict__ Wv,
                     const float* __restrict__ Wq, const float* __restrict__ Wk,
                     const float* __restrict__ Wo, const float* __restrict__ bv,
                     const float* __restrict__ bq, const float* __restrict__ bk,
                     bf16_t* __restrict__ xb, bf16_t* __restrict__ Wcat,
                     bf16_t* __restrict__ Wob, float* __restrict__ bcat) {
  const int blk = blockIdx.x, tid = threadIdx.x;
  const float* src; bf16_t* dst; int i;
  if (blk < 16384)      { src = x;           dst = xb;             i = (blk * 256 + tid) * 4; }
  else if (blk < 17408) { src = Wv;          dst = Wcat;           i = ((blk - 16384) * 256 + tid) * 4; }
  else if (blk < 17920) { src = Wq + 524288; dst = Wcat + 1048576; i = ((blk - 17408) * 256 + tid) * 4; }
  else if (blk < 18432) { src = Wk + 524288; dst = Wcat + 1572864; i = ((blk - 17920) * 256 + tid) * 4; }
  else if (blk < 19456) { src = Wo;          dst = Wob;            i = ((blk - 18432) * 256 + tid) * 4; }
  else {
    const int j = tid * 8;
#pragma unroll
    for (int k = 0; k < 8; ++k) {
      const int idx = j + k;
      float v;
      if (idx < 1024) v = bv[idx];
      else if (idx < 1536) v = bq[idx - 512];
      else v = bk[idx - 1024];
      bcat[idx] = v;
    }
    return;
  }
  float4 v = *(const float4*)(src + i);
  bf16x4 d = {(bf16_t)v.x, (bf16_t)v.y, (bf16_t)v.z, (bf16_t)v.w};
  *(bf16x4*)(dst + i) = d;
}

// ---------------------------------------------------------------------------
// 8-phase GEMM core (r3-verified). LDS chunk layout per buffer:
//   chunk c = oct*256 + idx  holds Mat[base+idx][tile*64 + oct*8 .. +8]
// ---------------------------------------------------------------------------
#define G8_DECL                                                                 \
  __shared__ bf16_t As[2][16384];                                               \
  __shared__ bf16_t Bs[2][16384];                                               \
  const int tid = threadIdx.x;                                                  \
  const int w = tid >> 6, l = tid & 63;                                         \
  const int lq = l >> 4, lm = l & 15;                                           \
  const int wr = (w >> 2) << 7;   /* wave row offset 0/128 */                   \
  const int wc = (w & 3) << 6;    /* wave col offset 0/64/128/192 */            \
  floatx4 acc[8][4];                                                            \
  { floatx4 z = {0.f, 0.f, 0.f, 0.f};                                           \
    _Pragma("unroll") for (int i = 0; i < 8; ++i)                               \
    _Pragma("unroll") for (int j = 0; j < 4; ++j) acc[i][j] = z; }              \
  const int t7 = tid & 127, t8 = tid >> 7;                                      \
  const int sbase = ((((w >> 1) << 8) + ((w & 1) << 6)) << 3);

#define G8_ST_A(s, off, jk)                                                     \
  glds16(pAt + (off),         &As[s][0] + ((jk) << 13) + sbase);                \
  glds16(pAt + aoff2 + (off), &As[s][0] + ((jk) << 13) + 1024 + sbase);
#define G8_ST_B(s, off, jk)                                                     \
  glds16(pBt + (off),          &Bs[s][0] + ((jk) << 13) + sbase);               \
  glds16(pBt + 131072 + (off), &Bs[s][0] + ((jk) << 13) + 1024 + sbase);

#define G8_READ_B(s, kk)                                                        \
  _Pragma("unroll") for (int nt = 0; nt < 4; ++nt)                              \
    bfr[nt] = *(const bf16x8*)(&Bs[s][0] +                                      \
        (((((kk) * 4 + lq) << 8) + wc + nt * 16 + lm) << 3));

#define G8_READ_A(s, kk, mh)                                                    \
  _Pragma("unroll") for (int i = 0; i < 4; ++i)                                 \
    af[i] = *(const bf16x8*)(&As[s][0] +                                        \
        (((((kk) * 4 + lq) << 8) + wr + (mh) * 64 + i * 16 + lm) << 3));

#define G8_MFMA(mh)                                                             \
  __builtin_amdgcn_s_setprio(1);                                                \
  _Pragma("unroll") for (int i = 0; i < 4; ++i)                                 \
    _Pragma("unroll") for (int nt = 0; nt < 4; ++nt)                            \
      acc[(mh) * 4 + i][nt] = MFMA16(af[i], bfr[nt], acc[(mh) * 4 + i][nt]);    \
  __builtin_amdgcn_s_setprio(0);

#define PH_PRE   SCHED0; SBAR; LGKMCNT0; SCHED0;
#define PH_POST  SCHED0; SBAR; SCHED0;

// r3-verified ledger: VMCNT(4)@ph2 retires prev ph5-8; VMCNT(8)@ph6 retires
// ph1-2; VMCNT(8)@ph8 retires ph3-4. Never 0 in main loop; tail peeled.
#define G8_ITER                                                                 \
    G8_READ_A(0, 0, 0) G8_READ_B(0, 0)                                          \
    G8_ST_A(1, 96, 1)                                                           \
    PH_PRE G8_MFMA(0) PH_POST                                                   \
    G8_READ_A(0, 0, 1)                                                          \
    G8_ST_B(1, 96, 1)                                                           \
    VMCNT(4);                                                                   \
    PH_PRE G8_MFMA(1) PH_POST                                                   \
    G8_READ_A(0, 1, 0) G8_READ_B(0, 1)                                          \
    G8_ST_A(0, 128, 0)                                                          \
    PH_PRE G8_MFMA(0) PH_POST                                                   \
    G8_READ_A(0, 1, 1)                                                          \
    G8_ST_B(0, 128, 0)                                                          \
    PH_PRE G8_MFMA(1) PH_POST                                                   \
    G8_READ_A(1, 0, 0) G8_READ_B(1, 0)                                          \
    G8_ST_A(0, 160, 1)                                                          \
    PH_PRE G8_MFMA(0) PH_POST                                                   \
    G8_READ_A(1, 0, 1)                                                          \
    G8_ST_B(0, 160, 1)                                                          \
    VMCNT(8);                                                                   \
    PH_PRE G8_MFMA(1) PH_POST                                                   \
    G8_READ_A(1, 1, 0) G8_READ_B(1, 1)                                          \
    G8_ST_A(1, 192, 0)                                                          \
    PH_PRE G8_MFMA(0) PH_POST                                                   \
    G8_READ_A(1, 1, 1)                                                          \
    G8_ST_B(1, 192, 0)                                                          \
    VMCNT(8);                                                                   \
    PH_PRE G8_MFMA(1) PH_POST

#define G8_TAIL                                                                 \
    G8_READ_A(0, 0, 0) G8_READ_B(0, 0)                                          \
    G8_ST_A(1, 96, 1)                                                           \
    PH_PRE G8_MFMA(0) PH_POST                                                   \
    G8_READ_A(0, 0, 1)                                                          \
    G8_ST_B(1, 96, 1)                                                           \
    VMCNT(4);                                                                   \
    PH_PRE G8_MFMA(1) PH_POST                                                   \
    G8_READ_A(0, 1, 0) G8_READ_B(0, 1)                                          \
    PH_PRE G8_MFMA(0) PH_POST                                                   \
    G8_READ_A(0, 1, 1)                                                          \
    PH_PRE G8_MFMA(1) PH_POST                                                   \
    G8_READ_A(1, 0, 0) G8_READ_B(1, 0)                                          \
    PH_PRE G8_MFMA(0) PH_POST                                                   \
    G8_READ_A(1, 0, 1)                                                          \
    VMCNT(0);                                                                   \
    PH_PRE G8_MFMA(1) PH_POST                                                   \
    G8_READ_A(1, 1, 0) G8_READ_B(1, 1)                                          \
    PH_PRE G8_MFMA(0) PH_POST                                                   \
    G8_READ_A(1, 1, 1)                                                          \
    PH_PRE G8_MFMA(1) PH_POST

#define G8_MAIN                                                                 \
  G8_ST_A(0, 0, 0) G8_ST_B(0, 0, 0)                                             \
  G8_ST_A(0, 32, 1) G8_ST_B(0, 32, 1)                                           \
  G8_ST_A(1, 64, 0) G8_ST_B(1, 64, 0)                                           \
  VMCNT(0); SBAR; SCHED0;                                                       \
  bf16x8 af[4], bfr[4];                                                         \
  for (int t = 0; t < 7; ++t) {                                                 \
    G8_ITER                                                                     \
    pAt += 128; pBt += 128;                                                     \
  }                                                                             \
  G8_TAIL

// ---- phase-2 variants: 256x128 half-tile, B = 128 rows (1 glds16/stage) ----
// B2 LDS layout: chunk c = oct*128 + row; dest = (jk<<12) + w*512 + lane*8.
#define G2_ST_B(s, off, jk)                                                     \
  glds16(pBt + (off), &Bs[s][0] + ((jk) << 12) + ((w) << 9));

#define G2_READ_B(s, kk)                                                        \
  _Pragma("unroll") for (int nt = 0; nt < 2; ++nt)                              \
    bfr[nt] = *(const bf16x8*)(&Bs[s][0] +                                      \
        (((((kk) * 4 + lq) << 7) + wc2 + nt * 16 + lm) << 3));

#define G2_MFMA(mh)                                                             \
  __builtin_amdgcn_s_setprio(1);                                                \
  _Pragma("unroll") for (int i = 0; i < 4; ++i)                                 \
    _Pragma("unroll") for (int nt = 0; nt < 2; ++nt)                            \
      acc[(mh) * 4 + i][nt] = MFMA16(af[i], bfr[nt], acc[(mh) * 4 + i][nt]);    \
  __builtin_amdgcn_s_setprio(0);

// Ledger ({A:2,B:1}/phase): VMCNT(3)@ph2 keeps ph1-2 (retires prev ph5-8);
// VMCNT(6)@ph6 keeps ph3-6 (retires ph1-2); VMCNT(6)@ph8 keeps ph5-8
// (retires ph3-4). Tail: VMCNT(3)@ph2 then VMCNT(0)@ph6.
#define G2_ITER                                                                 \
    G8_READ_A(0, 0, 0) G2_READ_B(0, 0)                                          \
    G8_ST_A(1, 96, 1)                                                           \
    PH_PRE G2_MFMA(0) PH_POST                                                   \
    G8_READ_A(0, 0, 1)                                                          \
    G2_ST_B(1, 96, 1)                                                           \
    VMCNT(3);                                                                   \
    PH_PRE G2_MFMA(1) PH_POST                                                   \
    G8_READ_A(0, 1, 0) G2_READ_B(0, 1)                                          \
    G8_ST_A(0, 128, 0)                                                          \
    PH_PRE G2_MFMA(0) PH_POST                                                   \
    G8_READ_A(0, 1, 1)                                                          \
    G2_ST_B(0, 128, 0)                                                          \
    PH_PRE G2_MFMA(1) PH_POST                                                   \
    G8_READ_A(1, 0, 0) G2_READ_B(1, 0)                                          \
    G8_ST_A(0, 160, 1)                                                          \
    PH_PRE G2_MFMA(0) PH_POST                                                   \
    G8_READ_A(1, 0, 1)                                                          \
    G2_ST_B(0, 160, 1)                                                          \
    VMCNT(6);                                                                   \
    PH_PRE G2_MFMA(1) PH_POST                                                   \
    G8_READ_A(1, 1, 0) G2_READ_B(1, 1)                                          \
    G8_ST_A(1, 192, 0)                                                          \
    PH_PRE G2_MFMA(0) PH_POST                                                   \
    G8_READ_A(1, 1, 1)                                                          \
    G2_ST_B(1, 192, 0)                                                          \
    VMCNT(6);                                                                   \
    PH_PRE G2_MFMA(1) PH_POST

#define G2_TAIL                                                                 \
    G8_READ_A(0, 0, 0) G2_READ_B(0, 0)                                          \
    G8_ST_A(1, 96, 1)                                                           \
    PH_PRE G2_MFMA(0) PH_POST                                                   \
    G8_READ_A(0, 0, 1)                                                          \
    G2_ST_B(1, 96, 1)                                                           \
    VMCNT(3);                                                                   \
    PH_PRE G2_MFMA(1) PH_POST                                                   \
    G8_READ_A(0, 1, 0) G2_READ_B(0, 1)                                          \
    PH_PRE G2_MFMA(0) PH_POST                                                   \
    G8_READ_A(0, 1, 1)                                                          \
    PH_PRE G2_MFMA(1) PH_POST                                                   \
    G8_READ_A(1, 0, 0) G2_READ_B(1, 0)                                          \
    PH_PRE G2_MFMA(0) PH_POST                                                   \
    G8_READ_A(1, 0, 1)                                                          \
    VMCNT(0);                                                                   \
    PH_PRE G2_MFMA(1) PH_POST                                                   \
    G8_READ_A(1, 1, 0) G2_READ_B(1, 1)                                          \
    PH_PRE G2_MFMA(0) PH_POST                                                   \
    G8_READ_A(1, 1, 1)                                                          \
    PH_PRE G2_MFMA(1) PH_POST

#define G2_MAIN                                                                 \
  G8_ST_A(0, 0, 0) G2_ST_B(0, 0, 0)                                             \
  G8_ST_A(0, 32, 1) G2_ST_B(0, 32, 1)                                           \
  G8_ST_A(1, 64, 0) G2_ST_B(1, 64, 0)                                           \
  VMCNT(0); SBAR; SCHED0;                                                       \
  for (int t = 0; t < 7; ++t) {                                                 \
    G2_ITER                                                                     \
    pAt += 128; pBt += 128;                                                     \
  }                                                                             \
  G2_TAIL

// ---------------------------------------------------------------------------
// gemm_fused: 256 blocks, each = 1 proj1 tile + 1 proj2 half-tile.
//  phase 1 (proj1): xcd=n&7; j=n>>3; row0=(xcd*8+(j&7))*256; ct=j>>3;
//    cols: ct<2 -> Wv-local [0,512) -> qkv ; ct>=2 -> Wq [1024,1536) -> qg.
//  phase 2 (proj2): jj=n>>3; row2=(xcd*4+(jj&3))*256 (packed); rem=jj>>2;
//    ct2=rem>>1, nh=rem&1; col2 = base(ct2)+nh*128;
//    packed row r -> global A row g = ((r>>5)<<6)+32+(r&31)  (subset of this
//    XCD's phase-1 band -> L2 hits); clamp r<=8063 (defensive).
// ---------------------------------------------------------------------------
__global__ __launch_bounds__(512, 2)
void gemm_fused(const bf16_t* __restrict__ A, const bf16_t* __restrict__ Wcat,
                const float* __restrict__ bcat, bf16_t* __restrict__ qkv,
                bf16_t* __restrict__ vg, bf16_t* __restrict__ qg,
                bf16_t* __restrict__ kg) {
  G8_DECL
  const int n = blockIdx.x;
  const int xcd = n & 7, j = n >> 3;
  const int ct = j >> 3;
  const long row0 = (long)(xcd * 8 + (j & 7)) * 256;   // [0,16384)
  const long col0 = ct * 256 + (ct >= 2 ? 512 : 0);
  int aoff2 = 131072;
  const bf16_t* pAt = A + (row0 + t7) * 1024 + t8 * 8;
  const bf16_t* pBt = Wcat + (col0 + t7) * 1024 + t8 * 8;
  G8_MAIN
  {
    bf16_t* dst; long ld, cofs;
    if (col0 < 512) { dst = qkv; ld = 1024; cofs = 0; }
    else            { dst = qg;  ld = 512;  cofs = 1024; }
#pragma unroll
    for (int nt = 0; nt < 4; ++nt) {
      const long col = col0 + wc + nt * 16 + lm;
      const float bc = bcat[col];
      const long cl = col - cofs;
#pragma unroll
      for (int mt = 0; mt < 8; ++mt) {
#pragma unroll
        for (int r = 0; r < 4; ++r) {
          const long row = row0 + wr + mt * 16 + lq * 4 + r;
          dst[row * ld + cl] = (bf16_t)(acc[mt][nt][r] + bc);
        }
      }
    }
  }
  // ---- phase 2: proj2 half-tile ----
  const int wc2 = (w & 3) << 5;   // wave col offset 0/32/64/96
  const int rem = j >> 2;         // 0..7
  const int ct2 = rem >> 1, nh = rem & 1;
  const long row2 = (long)(xcd * 4 + (j & 3)) * 256;   // packed [0,8192)
  const long col2 = ((ct2 < 2) ? (512 + ct2 * 256) : (1536 + (ct2 - 2) * 256)) + nh * 128;
  long r2 = row2 + t7;
  if (r2 > 8063) r2 = 8063;                             // defensive clamp
  const long g2 = ((r2 >> 5) << 6) + 32 + (r2 & 31);    // gathered global row
  pAt = A + g2 * 1024 + t8 * 8;
  aoff2 = 262144;                                       // +128 packed rows
  pBt = Wcat + (col2 + t7) * 1024 + t8 * 8;
  { floatx4 z = {0.f, 0.f, 0.f, 0.f};
#pragma unroll
    for (int i = 0; i < 8; ++i)
#pragma unroll
      for (int jz = 0; jz < 4; ++jz) acc[i][jz] = z; }
  G2_MAIN
  {
    bf16_t* dst2 = (ct2 < 2) ? vg : kg;
    const long cofs2 = (ct2 < 2) ? 512 : 1536;
#pragma unroll
    for (int nt = 0; nt < 2; ++nt) {
      const long col = col2 + wc2 + nt * 16 + lm;
      const float bc = bcat[col];
      const long cl = col - cofs2;
#pragma unroll
      for (int mt = 0; mt < 8; ++mt) {
#pragma unroll
        for (int r = 0; r < 4; ++r) {
          const long row = row2 + wr + mt * 16 + lq * 4 + r;
          dst2[row * 512 + cl] = (bf16_t)(acc[mt][nt][r] + bc);
        }
      }
    }
  }
}

// out-projection GEMM: M=16384, N=1024 -> 256 blocks, ROW-BAND swizzle.
__global__ __launch_bounds__(512, 2)
void gemm_bt(const bf16_t* __restrict__ A, const bf16_t* __restrict__ W,
             const float* __restrict__ bias, float* __restrict__ C, int ldc) {
  G8_DECL
  const int n = blockIdx.x, xcd = n & 7, j = n >> 3;  // j in [0,32)
  const long row0 = (long)(xcd * 8 + (j & 7)) * 256;  // [0,16384)
  const long col0 = (long)(j >> 3) * 256;             // [0,1024)
  const int aoff2 = 131072;
  const bf16_t* pAt = A + (row0 + t7) * 1024 + t8 * 8;
  const bf16_t* pBt = W + (col0 + t7) * 1024 + t8 * 8;
  G8_MAIN
#pragma unroll
  for (int nt = 0; nt < 4; ++nt) {
    const long col = col0 + wc + nt * 16 + lm;
    const float bc = bias[col];
#pragma unroll
    for (int mt = 0; mt < 8; ++mt) {
#pragma unroll
      for (int r = 0; r < 4; ++r) {
        const long row = row0 + wr + mt * 16 + lq * 4 + r;
        C[row * (long)ldc + col] = acc[mt][nt][r] + bc;
      }
    }
  }
}

// ---------------------------------------------------------------------------
// Sparse attention (r7-verified). Block = (qq, h, b): 512 query rows,
// 256 selected keys: token(lk) = 64*(lk>>2) + 32 + 4*h + (lk&3).
// kg/vg PACKED: packed row = ((lk>>2)<<5) + 4*h + (lk&3), 2048 rows/batch.
// 512 threads = 8 waves; K/V/mask staged once; each wave runs 4 independent
// 16-row q-passes with no cross-wave barriers (Ps is wave-private).
// ---------------------------------------------------------------------------
__global__ __launch_bounds__(512, 1)
void attn_sparse(const bf16_t* __restrict__ qg, const bf16_t* __restrict__ kg,
                 const bf16_t* __restrict__ vg, const int* __restrict__ mask,
                 bf16_t* __restrict__ qkv) {
  __shared__ bf16_t Ks[16384];        // frag-order: chunk = kq*256 + lkey (32KB)
  __shared__ bf16_t Vt[64 * 264];     // Vt[d][lkey], stride 264 (+8 pad) (33KB)
  __shared__ bf16_t Ps[8 * 16 * 136]; // per-wave P half-tile, stride 136 (34KB)
  __shared__ int smask[256];

  const int tid = threadIdx.x;
  const int b = blockIdx.z, h = blockIdx.y, qq = blockIdx.x;  // qq in [0,8)

  {
    const int lk = tid & 255;
    const int hf = tid >> 8;  // 0/1: split the 8 chunks between thread halves
    const int selrow = ((lk >> 2) << 5) + (h << 2) + (lk & 3);
    const size_t rowi = (size_t)(b * 2048 + selrow);
    const uint4* ksrc = (const uint4*)(kg + rowi * 512 + h * 64);
#pragma unroll
    for (int kq = 0; kq < 4; ++kq) {
      const int kq8 = hf * 4 + kq;
      *(uint4*)(Ks + (kq8 * 256 + lk) * 8) = ksrc[kq8];
    }
    const bf16_t* vsrc = vg + rowi * 512 + h * 64;
#pragma unroll
    for (int i = 0; i < 4; ++i) {
      const int i8 = hf * 4 + i;
      bf16x8 vv = *(const bf16x8*)(vsrc + i8 * 8);
#pragma unroll
      for (int j = 0; j < 8; ++j) Vt[(i8 * 8 + j) * 264 + lk] = vv[j];
    }
    if (tid < 256) {
      const int token = ((lk >> 2) << 6) + 32 + (h << 2) + (lk & 3);
      smask[lk] = mask[b * 4096 + token];
    }
  }
  __syncthreads();

  const int w = tid >> 6, l = tid & 63, lq = l >> 4, lm = l & 15;
  bf16_t* Pw = Ps + w * (16 * 136);
  floatx4 zero4 = {0.f, 0.f, 0.f, 0.f};

  for (int p = 0; p < 4; ++p) {
    const int mrow = (qq << 9) + ((p * 8 + w) << 4);  // 16-row q-tile base

    const bf16_t* qrow = qg + (size_t)(b * 4096 + mrow + lm) * 512 + h * 64 + lq * 8;
    bf16x8 aq0 = *(const bf16x8*)qrow;
    bf16x8 aq1 = *(const bf16x8*)(qrow + 32);

    floatx4 s[16];
#pragma unroll
    for (int t = 0; t < 16; ++t) {
      bf16x8 kb0 = *(const bf16x8*)(Ks + (lq * 256 + t * 16 + lm) * 8);
      bf16x8 kb1 = *(const bf16x8*)(Ks + ((4 + lq) * 256 + t * 16 + lm) * 8);
      floatx4 z = zero4;
      z = MFMA16(aq0, kb0, z);
      z = MFMA16(aq1, kb1, z);
      s[t] = z;
    }

    float rmax[4] = {-1e30f, -1e30f, -1e30f, -1e30f};
#pragma unroll
    for (int t = 0; t < 16; ++t) {
      const bool mk = smask[t * 16 + lm] != 0;
#pragma unroll
      for (int r = 0; r < 4; ++r) {
        float v = s[t][r] * 0.125f;
        v = mk ? -1e10f : v;
        s[t][r] = v;
        rmax[r] = fmaxf(rmax[r], v);
      }
    }
#pragma unroll
    for (int off = 1; off < 16; off <<= 1)
#pragma unroll
      for (int r = 0; r < 4; ++r) rmax[r] = fmaxf(rmax[r], __shfl_xor(rmax[r], off));
    float rsum[4] = {0.f, 0.f, 0.f, 0.f};
#pragma unroll
    for (int t = 0; t < 16; ++t)
#pragma unroll
      for (int r = 0; r < 4; ++r) {
        float pp = __expf(s[t][r] - rmax[r]);
        s[t][r] = pp;
        rsum[r] += pp;
      }
#pragma unroll
    for (int off = 1; off < 16; off <<= 1)
#pragma unroll
      for (int r = 0; r < 4; ++r) rsum[r] += __shfl_xor(rsum[r], off);
    float rinv[4];
#pragma unroll
    for (int r = 0; r < 4; ++r) rinv[r] = 1.0f / rsum[r];

    floatx4 o[4];
#pragma unroll
    for (int dt = 0; dt < 4; ++dt) o[dt] = zero4;
#pragma unroll
    for (int half = 0; half < 2; ++half) {
#pragma unroll
      for (int t = 0; t < 8; ++t) {
        const int tt = half * 8 + t;
#pragma unroll
        for (int r = 0; r < 4; ++r)
          Pw[(lq * 4 + r) * 136 + t * 16 + lm] = (bf16_t)(s[tt][r] * rinv[r]);
      }
      // Pw is wave-private: ds_write -> ds_read ordering is handled by the
      // compiler's lgkmcnt tracking; no block barrier needed.
#pragma unroll
      for (int ks = 0; ks < 4; ++ks) {
        bf16x8 pa = *(const bf16x8*)(Pw + lm * 136 + ks * 32 + lq * 8);
#pragma unroll
        for (int dt = 0; dt < 4; ++dt) {
          bf16x8 vb = *(const bf16x8*)(Vt + (dt * 16 + lm) * 264 + half * 128 + ks * 32 + lq * 8);
          o[dt] = MFMA16(pa, vb, o[dt]);
        }
      }
    }

#pragma unroll
    for (int dt = 0; dt < 4; ++dt) {
      const int d = dt * 16 + lm;
#pragma unroll
      for (int r = 0; r < 4; ++r) {
        const int token = mrow + lq * 4 + r;
        qkv[(size_t)(b * 4096 + token) * 1024 + 512 + h * 64 + d] = (bf16_t)o[dt][r];
      }
    }
  }
}

// ---------------------------------------------------------------------------
extern "C" void kernel_launch(void* const* d_in, const int* in_sizes, int n_in,
                              void* d_out, int out_size, void* d_ws, size_t ws_size,
                              hipStream_t stream) {
  const float* x   = (const float*)d_in[0];
  const int* mask  = (const int*)d_in[1];
  const float* Wq  = (const float*)d_in[2];
  const float* bq  = (const float*)d_in[3];
  const float* Wk  = (const float*)d_in[4];
  const float* bk  = (const float*)d_in[5];
  const float* Wv  = (const float*)d_in[6];
  const float* bv  = (const float*)d_in[7];
  const float* Wo  = (const float*)d_in[8];
  const float* bo  = (const float*)d_in[9];
  float* out = (float*)d_out;

  // ws: xb 32MB | Wcat 4MB | Wob 2MB | bcat 8KB | vg | qg | kg | qkv
  char* ws = (char*)d_ws;
  bf16_t* xb   = (bf16_t*)(ws);
  bf16_t* Wcat = (bf16_t*)(ws + 33554432L);
  bf16_t* Wob  = (bf16_t*)(ws + 37748736L);
  float*  bcat = (float*)(ws + 39845888L);
  bf16_t* vg   = (bf16_t*)(ws + 39854080L);   // packed 4x2048x512 bf16 = 8MB
  bf16_t* qg   = (bf16_t*)(ws + 56631296L);   // full 16384x512 bf16 = 16MB
  bf16_t* kg   = (bf16_t*)(ws + 73408512L);   // packed 4x2048x512 bf16 = 8MB
  bf16_t* qkv  = (bf16_t*)(ws + 90185728L);   // 16384x1024 bf16 = 32MB

  prep<<<19457, dim3(256), 0, stream>>>(x, Wv, Wq, Wk, Wo, bv, bq, bk,
                                        xb, Wcat, Wob, bcat);
  gemm_fused<<<256, dim3(512), 0, stream>>>(xb, Wcat, bcat, qkv, vg, qg, kg);
  attn_sparse<<<dim3(8, 8, 4), dim3(512), 0, stream>>>(qg, kg, vg, mask, qkv);
  gemm_bt<<<256, dim3(512), 0, stream>>>(qkv, Wob, bo, out, 1024);
}